// Round 1
// baseline (8448.862 us; speedup 1.0000x reference)
//
#include <hip/hip_runtime.h>
#include <math.h>

#define NN 100000
#define NE 1600000
#define DIM 128

// ---------------- degree / norm precompute ----------------
__global__ void k_zero(float* __restrict__ p, int n) {
    int i = blockIdx.x * blockDim.x + threadIdx.x;
    if (i < n) p[i] = 0.f;
}

__global__ void k_count(const int* __restrict__ dst, float* __restrict__ deg) {
    int e = blockIdx.x * blockDim.x + threadIdx.x;
    if (e < NE) atomicAdd(&deg[dst[e]], 1.f);
}

__global__ void k_dinv(float* __restrict__ deg) {
    int i = blockIdx.x * blockDim.x + threadIdx.x;
    if (i < NN) deg[i] = rsqrtf(1.f + deg[i]);
}

__global__ void k_norm(const int* __restrict__ src, const int* __restrict__ dst,
                       const float* __restrict__ dinv, float* __restrict__ norm) {
    int e = blockIdx.x * blockDim.x + threadIdx.x;
    if (e < NE) norm[e] = dinv[src[e]] * dinv[dst[e]];
}

// ---------------- dense transform: out[N,128] = (relu?)in[N,128] @ W[128,128] ----------------
template <bool RELU>
__global__ __launch_bounds__(256, 2) void k_gemm(const float* __restrict__ in,
                                                 const float* __restrict__ W,
                                                 float* __restrict__ out) {
    __shared__ float Wl[DIM * DIM];   // 64 KB
    __shared__ float rows[8 * DIM];   // 4 KB
    for (int i = threadIdx.x; i < DIM * DIM / 4; i += 256)
        reinterpret_cast<float4*>(Wl)[i] = reinterpret_cast<const float4*>(W)[i];

    const int r  = threadIdx.x >> 5;   // 0..7  (row within 8-row panel)
    const int c4 = threadIdx.x & 31;   // 0..31 (float4 column group)

    for (int rb = blockIdx.x * 8; rb < NN; rb += gridDim.x * 8) {
        __syncthreads();  // W ready (iter 0) / rows consumed (iter>0)
        float4 v = reinterpret_cast<const float4*>(in + (size_t)rb * DIM)[threadIdx.x];
        if (RELU) {
            v.x = fmaxf(v.x, 0.f); v.y = fmaxf(v.y, 0.f);
            v.z = fmaxf(v.z, 0.f); v.w = fmaxf(v.w, 0.f);
        }
        reinterpret_cast<float4*>(rows)[threadIdx.x] = v;
        __syncthreads();

        const float* rp = rows + r * DIM;
        float4 acc = make_float4(0.f, 0.f, 0.f, 0.f);
#pragma unroll 8
        for (int k = 0; k < DIM; ++k) {
            float xv = rp[k];
            float4 w = reinterpret_cast<const float4*>(Wl + k * DIM)[c4];
            acc.x = fmaf(xv, w.x, acc.x);
            acc.y = fmaf(xv, w.y, acc.y);
            acc.z = fmaf(xv, w.z, acc.z);
            acc.w = fmaf(xv, w.w, acc.w);
        }
        reinterpret_cast<float4*>(out + (size_t)(rb + r) * DIM)[c4] = acc;
    }
}

// ---------------- agg init: agg = h * dinv^2 + b ----------------
__global__ void k_selfinit(const float4* __restrict__ h4, const float* __restrict__ dinv,
                           const float* __restrict__ b, float4* __restrict__ agg4) {
    int i = blockIdx.x * blockDim.x + threadIdx.x;  // over NN*32 float4s
    if (i >= NN * 32) return;
    int n = i >> 5, c = i & 31;
    float s = dinv[n]; s = s * s;
    float4 h = h4[i];
    float4 bb = reinterpret_cast<const float4*>(b)[c];
    agg4[i] = make_float4(fmaf(h.x, s, bb.x), fmaf(h.y, s, bb.y),
                          fmaf(h.z, s, bb.z), fmaf(h.w, s, bb.w));
}

// ---------------- edge scatter: agg[dst] += h[src] * norm ----------------
__global__ void k_scatter(const float4* __restrict__ h4, const int* __restrict__ src,
                          const int* __restrict__ dst, const float* __restrict__ norm,
                          float* __restrict__ agg) {
    int t = blockIdx.x * blockDim.x + threadIdx.x;
    int e = t >> 5;  // 32 threads per edge
    if (e >= NE) return;
    int c = t & 31;
    int s = src[e], d = dst[e];
    float nm = norm[e];
    float4 v = h4[(size_t)s * 32 + c];
    float* o = agg + (size_t)d * DIM + c * 4;
    atomicAdd(o + 0, v.x * nm);
    atomicAdd(o + 1, v.y * nm);
    atomicAdd(o + 2, v.z * nm);
    atomicAdd(o + 3, v.w * nm);
}

// ---------------- mean pool (with relu) ----------------
__global__ void k_pool(const float* __restrict__ B, float* __restrict__ pooled) {
    int c = threadIdx.x;           // 0..127
    int r0 = blockIdx.x * 250;     // 400 blocks * 250 rows = 100000
    float s = 0.f;
    for (int r = r0; r < r0 + 250; ++r)
        s += fmaxf(B[(size_t)r * DIM + c], 0.f);
    atomicAdd(&pooled[c], s);
}

// ---------------- fc + softmax ----------------
__global__ void k_final(const float* __restrict__ pooled, const float* __restrict__ fc_w,
                        const float* __restrict__ fc_b, float* __restrict__ out) {
    __shared__ float part[4][DIM];
    int c = threadIdx.x;  // 0..127
    float p = pooled[c] * (1.f / NN);
    for (int j = 0; j < 4; ++j) part[j][c] = p * fc_w[c * 4 + j];
    __syncthreads();
    if (c == 0) {
        float l[4];
        for (int j = 0; j < 4; ++j) {
            float s = fc_b[j];
            for (int i = 0; i < DIM; ++i) s += part[j][i];
            l[j] = s;
        }
        float m = fmaxf(fmaxf(l[0], l[1]), fmaxf(l[2], l[3]));
        float e[4], Z = 0.f;
        for (int j = 0; j < 4; ++j) { e[j] = expf(l[j] - m); Z += e[j]; }
        for (int j = 0; j < 4; ++j) out[j] = e[j] / Z;
    }
}

extern "C" void kernel_launch(void* const* d_in, const int* in_sizes, int n_in,
                              void* d_out, int out_size, void* d_ws, size_t ws_size,
                              hipStream_t stream) {
    const float* x   = (const float*)d_in[0];
    const int*   ei  = (const int*)d_in[1];
    const float* W1  = (const float*)d_in[2];
    const float* b1  = (const float*)d_in[3];
    const float* W2  = (const float*)d_in[4];
    const float* b2  = (const float*)d_in[5];
    const float* W3  = (const float*)d_in[6];
    const float* b3  = (const float*)d_in[7];
    const float* fcw = (const float*)d_in[8];
    const float* fcb = (const float*)d_in[9];
    float* out = (float*)d_out;

    char* ws = (char*)d_ws;
    float* A      = (float*)(ws);                  // 51,200,000 B
    float* B      = (float*)(ws + 51200000);       // 51,200,000 B
    float* dinv   = (float*)(ws + 102400000);      //    400,000 B
    float* norm   = (float*)(ws + 102800000);      //  6,400,000 B
    float* pooled = (float*)(ws + 109200000);      //        512 B

    const int* src = ei;
    const int* dst = ei + NE;

    // degree / norm (reused across all 3 layers)
    k_zero<<<(NN + 255) / 256, 256, 0, stream>>>(dinv, NN);
    k_count<<<(NE + 255) / 256, 256, 0, stream>>>(dst, dinv);
    k_dinv<<<(NN + 255) / 256, 256, 0, stream>>>(dinv);
    k_norm<<<(NE + 255) / 256, 256, 0, stream>>>(src, dst, dinv, norm);

    // layer 1
    k_gemm<false><<<2500, 256, 0, stream>>>(x, W1, A);
    k_selfinit<<<12500, 256, 0, stream>>>((const float4*)A, dinv, b1, (float4*)B);
    k_scatter<<<200000, 256, 0, stream>>>((const float4*)A, src, dst, norm, B);
    // layer 2
    k_gemm<true><<<2500, 256, 0, stream>>>(B, W2, A);
    k_selfinit<<<12500, 256, 0, stream>>>((const float4*)A, dinv, b2, (float4*)B);
    k_scatter<<<200000, 256, 0, stream>>>((const float4*)A, src, dst, norm, B);
    // layer 3
    k_gemm<true><<<2500, 256, 0, stream>>>(B, W3, A);
    k_selfinit<<<12500, 256, 0, stream>>>((const float4*)A, dinv, b3, (float4*)B);
    k_scatter<<<200000, 256, 0, stream>>>((const float4*)A, src, dst, norm, B);

    // pool + fc + softmax
    k_zero<<<1, 128, 0, stream>>>(pooled, DIM);
    k_pool<<<400, 128, 0, stream>>>(B, pooled);
    k_final<<<1, 128, 0, stream>>>(pooled, fcw, fcb, out);
}

// Round 2
// 1118.683 us; speedup vs baseline: 7.5525x; 7.5525x over previous
//
#include <hip/hip_runtime.h>
#include <math.h>

#define NN 100000
#define NE 1600000
#define DIM 128

// ---------------- zero helpers ----------------
__global__ void k_zerof(float* __restrict__ p, int n) {
    int i = blockIdx.x * blockDim.x + threadIdx.x;
    if (i < n) p[i] = 0.f;
}
__global__ void k_zeroi(int* __restrict__ p, int n) {
    int i = blockIdx.x * blockDim.x + threadIdx.x;
    if (i < n) p[i] = 0;
}

// ---------------- degree count (int) ----------------
__global__ void k_counti(const int* __restrict__ dst, int* __restrict__ deg) {
    int e = blockIdx.x * blockDim.x + threadIdx.x;
    if (e < NE) atomicAdd(&deg[dst[e]], 1);
}

__global__ void k_dinv(const int* __restrict__ deg, float* __restrict__ dinv) {
    int i = blockIdx.x * blockDim.x + threadIdx.x;
    if (i < NN) dinv[i] = rsqrtf(1.f + (float)deg[i]);
}

// ---------------- exclusive scan of deg -> rowptr (and a copy for fill) ----------------
__global__ __launch_bounds__(1024) void k_scan(const int* __restrict__ deg,
                                               int* __restrict__ rowptr,
                                               int* __restrict__ fillptr) {
    __shared__ int sums[1024];
    const int tid = threadIdx.x;
    const int CH = (NN + 1023) / 1024;  // 98
    const int base = tid * CH;
    int s = 0;
    for (int i = 0; i < CH; ++i) { int idx = base + i; if (idx < NN) s += deg[idx]; }
    sums[tid] = s;
    __syncthreads();
    // Hillis-Steele inclusive scan over 1024 partials
    for (int off = 1; off < 1024; off <<= 1) {
        int v = (tid >= off) ? sums[tid - off] : 0;
        __syncthreads();
        sums[tid] += v;
        __syncthreads();
    }
    int off = sums[tid] - s;  // exclusive prefix of this chunk
    for (int i = 0; i < CH; ++i) {
        int idx = base + i;
        if (idx < NN) { rowptr[idx] = off; fillptr[idx] = off; off += deg[idx]; }
    }
}

// ---------------- CSR fill: bucket edges by dst ----------------
__global__ void k_fill(const int* __restrict__ src, const int* __restrict__ dst,
                       int* __restrict__ fillptr, int* __restrict__ esrc) {
    int e = blockIdx.x * blockDim.x + threadIdx.x;
    if (e < NE) {
        int d = dst[e];
        int pos = atomicAdd(&fillptr[d], 1);
        esrc[pos] = src[e];
    }
}

// ------- dense transform: g[N,128] = (relu?)(in) @ W * dinv[row]  -------
template <bool RELU>
__global__ __launch_bounds__(256, 2) void k_gemm(const float* __restrict__ in,
                                                 const float* __restrict__ W,
                                                 const float* __restrict__ dinv,
                                                 float* __restrict__ out) {
    __shared__ float Wl[DIM * DIM];   // 64 KB
    __shared__ float rows[8 * DIM];   // 4 KB
    for (int i = threadIdx.x; i < DIM * DIM / 4; i += 256)
        reinterpret_cast<float4*>(Wl)[i] = reinterpret_cast<const float4*>(W)[i];

    const int r  = threadIdx.x >> 5;   // 0..7  (row within 8-row panel)
    const int c4 = threadIdx.x & 31;   // 0..31 (float4 column group)

    for (int rb = blockIdx.x * 8; rb < NN; rb += gridDim.x * 8) {
        __syncthreads();  // W ready (iter 0) / rows consumed (iter>0)
        float4 v = reinterpret_cast<const float4*>(in + (size_t)rb * DIM)[threadIdx.x];
        if (RELU) {
            v.x = fmaxf(v.x, 0.f); v.y = fmaxf(v.y, 0.f);
            v.z = fmaxf(v.z, 0.f); v.w = fmaxf(v.w, 0.f);
        }
        reinterpret_cast<float4*>(rows)[threadIdx.x] = v;
        __syncthreads();

        const float* rp = rows + r * DIM;
        float4 acc = make_float4(0.f, 0.f, 0.f, 0.f);
#pragma unroll 8
        for (int k = 0; k < DIM; ++k) {
            float xv = rp[k];
            float4 w = reinterpret_cast<const float4*>(Wl + k * DIM)[c4];
            acc.x = fmaf(xv, w.x, acc.x);
            acc.y = fmaf(xv, w.y, acc.y);
            acc.z = fmaf(xv, w.z, acc.z);
            acc.w = fmaf(xv, w.w, acc.w);
        }
        float d = dinv[rb + r];
        acc.x *= d; acc.y *= d; acc.z *= d; acc.w *= d;
        reinterpret_cast<float4*>(out + (size_t)(rb + r) * DIM)[c4] = acc;
    }
}

// ------- gather-reduce: out[n] = dinv[n]*(g[n] + sum_{e:dst=n} g[src_e]) + b -------
__global__ __launch_bounds__(256) void k_gather(const float4* __restrict__ g4,
                                                const int* __restrict__ esrc,
                                                const int* __restrict__ rowptr,
                                                const int* __restrict__ rowend,
                                                const float* __restrict__ dinv,
                                                const float* __restrict__ bias,
                                                float4* __restrict__ out4) {
    int t = blockIdx.x * blockDim.x + threadIdx.x;
    int n = t >> 5;
    if (n >= NN) return;
    int c = t & 31;
    int j0 = rowptr[n], j1 = rowend[n];
    float di = dinv[n];
    float4 acc = g4[(size_t)n * 32 + c];  // self-loop term g[n]
    for (int j = j0; j < j1; ++j) {
        int s = esrc[j];  // same addr across the 32-lane group -> broadcast
        float4 v = g4[(size_t)s * 32 + c];
        acc.x += v.x; acc.y += v.y; acc.z += v.z; acc.w += v.w;
    }
    float4 bb = reinterpret_cast<const float4*>(bias)[c];
    out4[(size_t)n * 32 + c] = make_float4(fmaf(acc.x, di, bb.x), fmaf(acc.y, di, bb.y),
                                           fmaf(acc.z, di, bb.z), fmaf(acc.w, di, bb.w));
}

// ---------------- mean pool (with relu) ----------------
__global__ void k_pool(const float* __restrict__ B, float* __restrict__ pooled) {
    int c = threadIdx.x;           // 0..127
    int r0 = blockIdx.x * 250;     // 400 blocks * 250 rows = 100000
    float s = 0.f;
    for (int r = r0; r < r0 + 250; ++r)
        s += fmaxf(B[(size_t)r * DIM + c], 0.f);
    atomicAdd(&pooled[c], s);
}

// ---------------- fc + softmax ----------------
__global__ void k_final(const float* __restrict__ pooled, const float* __restrict__ fc_w,
                        const float* __restrict__ fc_b, float* __restrict__ out) {
    __shared__ float part[4][DIM];
    int c = threadIdx.x;  // 0..127
    float p = pooled[c] * (1.f / NN);
    for (int j = 0; j < 4; ++j) part[j][c] = p * fc_w[c * 4 + j];
    __syncthreads();
    if (c == 0) {
        float l[4];
        for (int j = 0; j < 4; ++j) {
            float s = fc_b[j];
            for (int i = 0; i < DIM; ++i) s += part[j][i];
            l[j] = s;
        }
        float m = fmaxf(fmaxf(l[0], l[1]), fmaxf(l[2], l[3]));
        float e[4], Z = 0.f;
        for (int j = 0; j < 4; ++j) { e[j] = expf(l[j] - m); Z += e[j]; }
        for (int j = 0; j < 4; ++j) out[j] = e[j] / Z;
    }
}

extern "C" void kernel_launch(void* const* d_in, const int* in_sizes, int n_in,
                              void* d_out, int out_size, void* d_ws, size_t ws_size,
                              hipStream_t stream) {
    const float* x   = (const float*)d_in[0];
    const int*   ei  = (const int*)d_in[1];
    const float* W1  = (const float*)d_in[2];
    const float* b1  = (const float*)d_in[3];
    const float* W2  = (const float*)d_in[4];
    const float* b2  = (const float*)d_in[5];
    const float* W3  = (const float*)d_in[6];
    const float* b3  = (const float*)d_in[7];
    const float* fcw = (const float*)d_in[8];
    const float* fcb = (const float*)d_in[9];
    float* out = (float*)d_out;

    char* ws = (char*)d_ws;
    float* A       = (float*)(ws);                  // 51,200,000 B
    float* B       = (float*)(ws + 51200000);       // 51,200,000 B
    float* dinv    = (float*)(ws + 102400000);      //    400,000 B
    int*   deg     = (int*)  (ws + 102800000);      //    400,000 B
    int*   rowptr  = (int*)  (ws + 103200000);      //    400,000 B
    int*   fillptr = (int*)  (ws + 103600000);      //    400,000 B
    int*   esrc    = (int*)  (ws + 104000000);      //  6,400,000 B
    float* pooled  = (float*)(ws + 110400000);      //        512 B

    const int* src = ei;
    const int* dst = ei + NE;

    // ---- CSR build (once; reused across all 3 layers) ----
    k_zeroi<<<(NN + 255) / 256, 256, 0, stream>>>(deg, NN);
    k_counti<<<(NE + 255) / 256, 256, 0, stream>>>(dst, deg);
    k_dinv<<<(NN + 255) / 256, 256, 0, stream>>>(deg, dinv);
    k_scan<<<1, 1024, 0, stream>>>(deg, rowptr, fillptr);
    k_fill<<<(NE + 255) / 256, 256, 0, stream>>>(src, dst, fillptr, esrc);
    // after k_fill, fillptr[n] == rowptr[n] + deg[n] == row end

    // ---- layer 1 ----
    k_gemm<false><<<2500, 256, 0, stream>>>(x, W1, dinv, A);
    k_gather<<<12500, 256, 0, stream>>>((const float4*)A, esrc, rowptr, fillptr, dinv, b1, (float4*)B);
    // ---- layer 2 ----
    k_gemm<true><<<2500, 256, 0, stream>>>(B, W2, dinv, A);
    k_gather<<<12500, 256, 0, stream>>>((const float4*)A, esrc, rowptr, fillptr, dinv, b2, (float4*)B);
    // ---- layer 3 ----
    k_gemm<true><<<2500, 256, 0, stream>>>(B, W3, dinv, A);
    k_gather<<<12500, 256, 0, stream>>>((const float4*)A, esrc, rowptr, fillptr, dinv, b3, (float4*)B);

    // ---- pool + fc + softmax ----
    k_zerof<<<1, 128, 0, stream>>>(pooled, DIM);
    k_pool<<<400, 128, 0, stream>>>(B, pooled);
    k_final<<<1, 128, 0, stream>>>(pooled, fcw, fcb, out);
}

// Round 3
// 861.062 us; speedup vs baseline: 9.8121x; 1.2992x over previous
//
#include <hip/hip_runtime.h>
#include <math.h>

#define NN 100000
#define NE 1600000
#define DIM 128
#define SCAN_B 98   // ceil(100000/1024)

// ---------------- zero helpers ----------------
__global__ void k_zerof(float* __restrict__ p, int n) {
    int i = blockIdx.x * blockDim.x + threadIdx.x;
    if (i < n) p[i] = 0.f;
}
__global__ void k_zeroi(int* __restrict__ p, int n) {
    int i = blockIdx.x * blockDim.x + threadIdx.x;
    if (i < n) p[i] = 0;
}

// ---------------- degree count (int) ----------------
__global__ void k_counti(const int* __restrict__ dst, int* __restrict__ deg) {
    int e = blockIdx.x * blockDim.x + threadIdx.x;
    if (e < NE) atomicAdd(&deg[dst[e]], 1);
}

__global__ void k_dinv(const int* __restrict__ deg, float* __restrict__ dinv) {
    int i = blockIdx.x * blockDim.x + threadIdx.x;
    if (i < NN) dinv[i] = rsqrtf(1.f + (float)deg[i]);
}

// ---------------- parallel exclusive scan (3 phases) ----------------
__global__ __launch_bounds__(1024) void k_scan1(const int* __restrict__ deg,
                                                int* __restrict__ bsum) {
    __shared__ int red[1024];
    int i = blockIdx.x * 1024 + threadIdx.x;
    red[threadIdx.x] = (i < NN) ? deg[i] : 0;
    __syncthreads();
    for (int off = 512; off > 0; off >>= 1) {
        if (threadIdx.x < off) red[threadIdx.x] += red[threadIdx.x + off];
        __syncthreads();
    }
    if (threadIdx.x == 0) bsum[blockIdx.x] = red[0];
}

__global__ void k_scan2(const int* __restrict__ bsum, int* __restrict__ boff) {
    if (threadIdx.x == 0) {
        int acc = 0;
        for (int b = 0; b < SCAN_B; ++b) { boff[b] = acc; acc += bsum[b]; }
    }
}

__global__ __launch_bounds__(1024) void k_scan3(const int* __restrict__ deg,
                                                const int* __restrict__ boff,
                                                int* __restrict__ rowptr,
                                                int* __restrict__ fillptr) {
    __shared__ int s[1024];
    int i = blockIdx.x * 1024 + threadIdx.x;
    int v = (i < NN) ? deg[i] : 0;
    s[threadIdx.x] = v;
    __syncthreads();
    // inclusive Hillis-Steele over the block
    for (int off = 1; off < 1024; off <<= 1) {
        int t = (threadIdx.x >= off) ? s[threadIdx.x - off] : 0;
        __syncthreads();
        s[threadIdx.x] += t;
        __syncthreads();
    }
    if (i < NN) {
        int ex = s[threadIdx.x] - v + boff[blockIdx.x];
        rowptr[i] = ex;
        fillptr[i] = ex;
    }
}

// ---------------- CSR fill: bucket edges by dst ----------------
__global__ void k_fill(const int* __restrict__ src, const int* __restrict__ dst,
                       int* __restrict__ fillptr, int* __restrict__ esrc) {
    int e = blockIdx.x * blockDim.x + threadIdx.x;
    if (e < NE) {
        int d = dst[e];
        int pos = atomicAdd(&fillptr[d], 1);
        esrc[pos] = src[e];
    }
}

// ------- dense transform: g[N,128] = (relu?)(in) @ W * dinv[row]  -------
template <bool RELU>
__global__ __launch_bounds__(256, 2) void k_gemm(const float* __restrict__ in,
                                                 const float* __restrict__ W,
                                                 const float* __restrict__ dinv,
                                                 float* __restrict__ out) {
    __shared__ float Wl[DIM * DIM];   // 64 KB
    __shared__ float rows[8 * DIM];   // 4 KB
    for (int i = threadIdx.x; i < DIM * DIM / 4; i += 256)
        reinterpret_cast<float4*>(Wl)[i] = reinterpret_cast<const float4*>(W)[i];

    const int r  = threadIdx.x >> 5;   // 0..7
    const int c4 = threadIdx.x & 31;   // 0..31

    for (int rb = blockIdx.x * 8; rb < NN; rb += gridDim.x * 8) {
        __syncthreads();
        float4 v = reinterpret_cast<const float4*>(in + (size_t)rb * DIM)[threadIdx.x];
        if (RELU) {
            v.x = fmaxf(v.x, 0.f); v.y = fmaxf(v.y, 0.f);
            v.z = fmaxf(v.z, 0.f); v.w = fmaxf(v.w, 0.f);
        }
        reinterpret_cast<float4*>(rows)[threadIdx.x] = v;
        __syncthreads();

        const float* rp = rows + r * DIM;
        float4 acc = make_float4(0.f, 0.f, 0.f, 0.f);
#pragma unroll 8
        for (int k = 0; k < DIM; ++k) {
            float xv = rp[k];
            float4 w = reinterpret_cast<const float4*>(Wl + k * DIM)[c4];
            acc.x = fmaf(xv, w.x, acc.x);
            acc.y = fmaf(xv, w.y, acc.y);
            acc.z = fmaf(xv, w.z, acc.z);
            acc.w = fmaf(xv, w.w, acc.w);
        }
        float d = dinv[rb + r];
        acc.x *= d; acc.y *= d; acc.z *= d; acc.w *= d;
        reinterpret_cast<float4*>(out + (size_t)(rb + r) * DIM)[c4] = acc;
    }
}

// ------- gather-reduce: out[n] = dinv[n]*(g[n] + sum_{e:dst=n} g[src_e]) + b -------
__global__ __launch_bounds__(256) void k_gather(const float4* __restrict__ g4,
                                                const int* __restrict__ esrc,
                                                const int* __restrict__ rowptr,
                                                const int* __restrict__ rowend,
                                                const float* __restrict__ dinv,
                                                const float* __restrict__ bias,
                                                float4* __restrict__ out4) {
    int t = blockIdx.x * blockDim.x + threadIdx.x;
    int n = t >> 5;
    if (n >= NN) return;
    int c = t & 31;
    int j0 = rowptr[n], j1 = rowend[n];
    float di = dinv[n];
    float4 acc = g4[(size_t)n * 32 + c];  // self-loop term g[n]

    int j = j0;
    for (; j + 4 <= j1; j += 4) {
        int s0 = esrc[j], s1 = esrc[j + 1], s2 = esrc[j + 2], s3 = esrc[j + 3];
        float4 v0 = g4[(size_t)s0 * 32 + c];
        float4 v1 = g4[(size_t)s1 * 32 + c];
        float4 v2 = g4[(size_t)s2 * 32 + c];
        float4 v3 = g4[(size_t)s3 * 32 + c];
        acc.x += (v0.x + v1.x) + (v2.x + v3.x);
        acc.y += (v0.y + v1.y) + (v2.y + v3.y);
        acc.z += (v0.z + v1.z) + (v2.z + v3.z);
        acc.w += (v0.w + v1.w) + (v2.w + v3.w);
    }
    for (; j < j1; ++j) {
        int s = esrc[j];
        float4 v = g4[(size_t)s * 32 + c];
        acc.x += v.x; acc.y += v.y; acc.z += v.z; acc.w += v.w;
    }
    float4 bb = reinterpret_cast<const float4*>(bias)[c];
    out4[(size_t)n * 32 + c] = make_float4(fmaf(acc.x, di, bb.x), fmaf(acc.y, di, bb.y),
                                           fmaf(acc.z, di, bb.z), fmaf(acc.w, di, bb.w));
}

// ---------------- mean pool (with relu) ----------------
__global__ void k_pool(const float* __restrict__ B, float* __restrict__ pooled) {
    int c = threadIdx.x;           // 0..127
    int r0 = blockIdx.x * 100;     // 1000 blocks * 100 rows
    float s = 0.f;
    for (int r = r0; r < r0 + 100; ++r)
        s += fmaxf(B[(size_t)r * DIM + c], 0.f);
    atomicAdd(&pooled[c], s);
}

// ---------------- fc + softmax ----------------
__global__ void k_final(const float* __restrict__ pooled, const float* __restrict__ fc_w,
                        const float* __restrict__ fc_b, float* __restrict__ out) {
    __shared__ float part[4][DIM];
    int c = threadIdx.x;  // 0..127
    float p = pooled[c] * (1.f / NN);
    for (int j = 0; j < 4; ++j) part[j][c] = p * fc_w[c * 4 + j];
    __syncthreads();
    if (c == 0) {
        float l[4];
        for (int j = 0; j < 4; ++j) {
            float s = fc_b[j];
            for (int i = 0; i < DIM; ++i) s += part[j][i];
            l[j] = s;
        }
        float m = fmaxf(fmaxf(l[0], l[1]), fmaxf(l[2], l[3]));
        float e[4], Z = 0.f;
        for (int j = 0; j < 4; ++j) { e[j] = expf(l[j] - m); Z += e[j]; }
        for (int j = 0; j < 4; ++j) out[j] = e[j] / Z;
    }
}

extern "C" void kernel_launch(void* const* d_in, const int* in_sizes, int n_in,
                              void* d_out, int out_size, void* d_ws, size_t ws_size,
                              hipStream_t stream) {
    const float* x   = (const float*)d_in[0];
    const int*   ei  = (const int*)d_in[1];
    const float* W1  = (const float*)d_in[2];
    const float* b1  = (const float*)d_in[3];
    const float* W2  = (const float*)d_in[4];
    const float* b2  = (const float*)d_in[5];
    const float* W3  = (const float*)d_in[6];
    const float* b3  = (const float*)d_in[7];
    const float* fcw = (const float*)d_in[8];
    const float* fcb = (const float*)d_in[9];
    float* out = (float*)d_out;

    char* ws = (char*)d_ws;
    float* A       = (float*)(ws);                  // 51,200,000 B
    float* B       = (float*)(ws + 51200000);       // 51,200,000 B
    float* dinv    = (float*)(ws + 102400000);      //    400,000 B
    int*   deg     = (int*)  (ws + 102800000);      //    400,000 B
    int*   rowptr  = (int*)  (ws + 103200000);      //    400,000 B
    int*   fillptr = (int*)  (ws + 103600000);      //    400,000 B
    int*   esrc    = (int*)  (ws + 104000000);      //  6,400,000 B
    int*   bsum    = (int*)  (ws + 110400000);      //        512 B
    int*   boff    = (int*)  (ws + 110401024);      //        512 B
    float* pooled  = (float*)(ws + 110402048);      //        512 B

    const int* src = ei;
    const int* dst = ei + NE;

    // ---- CSR build (once; reused across all 3 layers) ----
    k_zeroi<<<(NN + 255) / 256, 256, 0, stream>>>(deg, NN);
    k_counti<<<(NE + 255) / 256, 256, 0, stream>>>(dst, deg);
    k_dinv<<<(NN + 255) / 256, 256, 0, stream>>>(deg, dinv);
    k_scan1<<<SCAN_B, 1024, 0, stream>>>(deg, bsum);
    k_scan2<<<1, 64, 0, stream>>>(bsum, boff);
    k_scan3<<<SCAN_B, 1024, 0, stream>>>(deg, boff, rowptr, fillptr);
    k_fill<<<(NE + 255) / 256, 256, 0, stream>>>(src, dst, fillptr, esrc);
    // after k_fill, fillptr[n] == rowptr[n] + deg[n] == row end

    // ---- layer 1 ----
    k_gemm<false><<<2500, 256, 0, stream>>>(x, W1, dinv, A);
    k_gather<<<12500, 256, 0, stream>>>((const float4*)A, esrc, rowptr, fillptr, dinv, b1, (float4*)B);
    // ---- layer 2 ----
    k_gemm<true><<<2500, 256, 0, stream>>>(B, W2, dinv, A);
    k_gather<<<12500, 256, 0, stream>>>((const float4*)A, esrc, rowptr, fillptr, dinv, b2, (float4*)B);
    // ---- layer 3 ----
    k_gemm<true><<<2500, 256, 0, stream>>>(B, W3, dinv, A);
    k_gather<<<12500, 256, 0, stream>>>((const float4*)A, esrc, rowptr, fillptr, dinv, b3, (float4*)B);

    // ---- pool + fc + softmax ----
    k_zerof<<<1, 128, 0, stream>>>(pooled, DIM);
    k_pool<<<1000, 128, 0, stream>>>(B, pooled);
    k_final<<<1, 128, 0, stream>>>(pooled, fcw, fcb, out);
}

// Round 4
// 490.305 us; speedup vs baseline: 17.2319x; 1.7562x over previous
//
#include <hip/hip_runtime.h>
#include <math.h>

#define NN 100000
#define NE 1600000
#define DIM 128
#define SCAN_B 98   // ceil(100000/1024)

typedef __attribute__((ext_vector_type(8))) short short8;
typedef __attribute__((ext_vector_type(4))) float f32x4;

// ---- bf16 helpers (OCP bf16 as raw ushort) ----
__device__ __forceinline__ unsigned short f2b(float f) {   // RNE
    unsigned int b = __builtin_bit_cast(unsigned int, f);
    b += 0x7fffu + ((b >> 16) & 1u);
    return (unsigned short)(b >> 16);
}
__device__ __forceinline__ float blo(unsigned int u) { return __builtin_bit_cast(float, u << 16); }
__device__ __forceinline__ float bhi(unsigned int u) { return __builtin_bit_cast(float, u & 0xffff0000u); }
__device__ __forceinline__ unsigned int relu2(unsigned int v) {  // relu on packed 2xbf16
    unsigned int keep = ((~v) & 0x80008000u) >> 15;  // 1 per non-negative half
    return v & (keep * 0xffffu);
}
__device__ __forceinline__ void acc8(const uint4 v, float* a) {
    a[0] += blo(v.x); a[1] += bhi(v.x);
    a[2] += blo(v.y); a[3] += bhi(v.y);
    a[4] += blo(v.z); a[5] += bhi(v.z);
    a[6] += blo(v.w); a[7] += bhi(v.w);
}

// ---------------- zero helpers ----------------
__global__ void k_zerof(float* __restrict__ p, int n) {
    int i = blockIdx.x * blockDim.x + threadIdx.x;
    if (i < n) p[i] = 0.f;
}
__global__ void k_zeroi(int* __restrict__ p, int n) {
    int i = blockIdx.x * blockDim.x + threadIdx.x;
    if (i < n) p[i] = 0;
}

// ---------------- degree count (int) ----------------
__global__ void k_counti(const int* __restrict__ dst, int* __restrict__ deg) {
    int e = blockIdx.x * blockDim.x + threadIdx.x;
    if (e < NE) atomicAdd(&deg[dst[e]], 1);
}

__global__ void k_dinv(const int* __restrict__ deg, float* __restrict__ dinv) {
    int i = blockIdx.x * blockDim.x + threadIdx.x;
    if (i < NN) dinv[i] = rsqrtf(1.f + (float)deg[i]);
}

// ---------------- parallel exclusive scan (3 phases) ----------------
__global__ __launch_bounds__(1024) void k_scan1(const int* __restrict__ deg,
                                                int* __restrict__ bsum) {
    __shared__ int red[1024];
    int i = blockIdx.x * 1024 + threadIdx.x;
    red[threadIdx.x] = (i < NN) ? deg[i] : 0;
    __syncthreads();
    for (int off = 512; off > 0; off >>= 1) {
        if (threadIdx.x < off) red[threadIdx.x] += red[threadIdx.x + off];
        __syncthreads();
    }
    if (threadIdx.x == 0) bsum[blockIdx.x] = red[0];
}

__global__ void k_scan2(const int* __restrict__ bsum, int* __restrict__ boff) {
    if (threadIdx.x == 0) {
        int acc = 0;
        for (int b = 0; b < SCAN_B; ++b) { boff[b] = acc; acc += bsum[b]; }
    }
}

__global__ __launch_bounds__(1024) void k_scan3(const int* __restrict__ deg,
                                                const int* __restrict__ boff,
                                                int* __restrict__ rowptr,
                                                int* __restrict__ fillptr) {
    __shared__ int s[1024];
    int i = blockIdx.x * 1024 + threadIdx.x;
    int v = (i < NN) ? deg[i] : 0;
    s[threadIdx.x] = v;
    __syncthreads();
    for (int off = 1; off < 1024; off <<= 1) {
        int t = (threadIdx.x >= off) ? s[threadIdx.x - off] : 0;
        __syncthreads();
        s[threadIdx.x] += t;
        __syncthreads();
    }
    if (i < NN) {
        int ex = s[threadIdx.x] - v + boff[blockIdx.x];
        rowptr[i] = ex;
        fillptr[i] = ex;
    }
}

// ---------------- CSR fill: bucket edges by dst ----------------
__global__ void k_fill(const int* __restrict__ src, const int* __restrict__ dst,
                       int* __restrict__ fillptr, int* __restrict__ esrc) {
    int e = blockIdx.x * blockDim.x + threadIdx.x;
    if (e < NE) {
        int d = dst[e];
        int pos = atomicAdd(&fillptr[d], 1);
        esrc[pos] = src[e];
    }
}

// ------- MFMA transform: g[N,128](bf16) = (relu?)(in) @ W * dinv[row] -------
// block = 256 threads = 4 waves; 64 rows/block; 16x16x32 bf16 MFMA.
// LDS tiles XOR-swizzled at 16B-chunk granularity: chunk = base ^ (row&7).
template <bool F32IN>
__global__ __launch_bounds__(256) void k_gemm(const void* __restrict__ inp,
                                              const float* __restrict__ W,
                                              const float* __restrict__ dinv,
                                              uint4* __restrict__ out16) {
    __shared__ short Wt[DIM * DIM];   // [col][k] bf16, swizzled  (32 KB)
    __shared__ short Xb[64 * DIM];    // [row][k] bf16, swizzled; reused for output (16 KB)
    const int tid = threadIdx.x;
    const int rb = blockIdx.x * 64;

    // stage W transposed: Wt[c][k] = W[k][c]
    for (int idx = tid; idx < DIM * 16; idx += 256) {
        int c  = idx & 127;
        int kc = idx >> 7;  // 0..15 (this loop: kc = (idx>>7) + 2*iter), covers 0..15 over 8 iters
        uint4 p;
        p.x = (unsigned)f2b(W[(kc * 8 + 0) * DIM + c]) | ((unsigned)f2b(W[(kc * 8 + 1) * DIM + c]) << 16);
        p.y = (unsigned)f2b(W[(kc * 8 + 2) * DIM + c]) | ((unsigned)f2b(W[(kc * 8 + 3) * DIM + c]) << 16);
        p.z = (unsigned)f2b(W[(kc * 8 + 4) * DIM + c]) | ((unsigned)f2b(W[(kc * 8 + 5) * DIM + c]) << 16);
        p.w = (unsigned)f2b(W[(kc * 8 + 6) * DIM + c]) | ((unsigned)f2b(W[(kc * 8 + 7) * DIM + c]) << 16);
        int chunk = c * 16 + (kc ^ (c & 7));
        *reinterpret_cast<uint4*>(&Wt[chunk * 8]) = p;
    }
    // stage X rows rb..rb+63
    for (int idx = tid; idx < 64 * 16; idx += 256) {
        int row = idx >> 4, kc = idx & 15;
        int grow = rb + row;
        uint4 p = make_uint4(0u, 0u, 0u, 0u);
        if (grow < NN) {
            if (F32IN) {
                const float* xp = (const float*)inp + (size_t)grow * DIM + kc * 8;
                p.x = (unsigned)f2b(xp[0]) | ((unsigned)f2b(xp[1]) << 16);
                p.y = (unsigned)f2b(xp[2]) | ((unsigned)f2b(xp[3]) << 16);
                p.z = (unsigned)f2b(xp[4]) | ((unsigned)f2b(xp[5]) << 16);
                p.w = (unsigned)f2b(xp[6]) | ((unsigned)f2b(xp[7]) << 16);
            } else {
                uint4 v = ((const uint4*)inp)[(size_t)grow * 16 + kc];
                p.x = relu2(v.x); p.y = relu2(v.y); p.z = relu2(v.z); p.w = relu2(v.w);
            }
        }
        int chunk = row * 16 + (kc ^ (row & 7));
        *reinterpret_cast<uint4*>(&Xb[chunk * 8]) = p;
    }
    __syncthreads();

    const int lane = tid & 63;
    const int w    = tid >> 6;     // wave 0..3 -> rows w*16..w*16+15
    const int l15  = lane & 15;
    const int kg   = lane >> 4;    // 0..3
    f32x4 acc[8];
#pragma unroll
    for (int i = 0; i < 8; ++i) acc[i] = (f32x4){0.f, 0.f, 0.f, 0.f};

    const int arow = w * 16 + l15;
#pragma unroll
    for (int ks = 0; ks < 4; ++ks) {
        int kc = ks * 4 + kg;
        short8 a = *reinterpret_cast<const short8*>(&Xb[(arow * 16 + (kc ^ (arow & 7))) * 8]);
#pragma unroll
        for (int ct = 0; ct < 8; ++ct) {
            int col = ct * 16 + l15;
            short8 b = *reinterpret_cast<const short8*>(&Wt[(col * 16 + (kc ^ (col & 7))) * 8]);
            acc[ct] = __builtin_amdgcn_mfma_f32_16x16x32_bf16(a, b, acc[ct], 0, 0, 0);
        }
    }
    __syncthreads();   // all waves done reading Xb

    // epilogue: C[row = w*16 + kg*4 + reg][col = ct*16 + l15]; scale, bf16, stage
    float dv[4];
#pragma unroll
    for (int reg = 0; reg < 4; ++reg) {
        int grow = rb + w * 16 + kg * 4 + reg;
        dv[reg] = (grow < NN) ? dinv[grow] : 0.f;
    }
#pragma unroll
    for (int ct = 0; ct < 8; ++ct) {
        int col = ct * 16 + l15;
#pragma unroll
        for (int reg = 0; reg < 4; ++reg) {
            int row = w * 16 + kg * 4 + reg;
            Xb[row * DIM + (((col >> 3) ^ (row & 7)) << 3) + (col & 7)] =
                (short)f2b(acc[ct][reg] * dv[reg]);
        }
    }
    __syncthreads();

    // coalesced bf16 store
    for (int idx = tid; idx < 64 * 16; idx += 256) {
        int row = idx >> 4, kc = idx & 15;
        int grow = rb + row;
        if (grow < NN)
            out16[(size_t)grow * 16 + kc] =
                *reinterpret_cast<const uint4*>(&Xb[(row * 16 + (kc ^ (row & 7))) * 8]);
    }
}

// ------- gather-reduce (bf16 rows): out[n] = dinv[n]*(g[n] + sum g[src]) + b -------
__global__ __launch_bounds__(256) void k_gather(const uint4* __restrict__ g16,
                                                const int* __restrict__ esrc,
                                                const int* __restrict__ rowptr,
                                                const int* __restrict__ rowend,
                                                const float* __restrict__ dinv,
                                                const float* __restrict__ bias,
                                                uint4* __restrict__ out16) {
    int t = blockIdx.x * 256 + threadIdx.x;
    int n = t >> 4;          // 16 lanes per node
    if (n >= NN) return;
    int c = t & 15;          // 16B chunk (8 bf16 cols)
    int j0 = rowptr[n], j1 = rowend[n];
    float a[8];
    uint4 sv = g16[(size_t)n * 16 + c];  // self term
    a[0] = blo(sv.x); a[1] = bhi(sv.x); a[2] = blo(sv.y); a[3] = bhi(sv.y);
    a[4] = blo(sv.z); a[5] = bhi(sv.z); a[6] = blo(sv.w); a[7] = bhi(sv.w);
    int j = j0;
    for (; j + 4 <= j1; j += 4) {
        int s0 = esrc[j], s1 = esrc[j + 1], s2 = esrc[j + 2], s3 = esrc[j + 3];
        uint4 v0 = g16[(size_t)s0 * 16 + c];
        uint4 v1 = g16[(size_t)s1 * 16 + c];
        uint4 v2 = g16[(size_t)s2 * 16 + c];
        uint4 v3 = g16[(size_t)s3 * 16 + c];
        acc8(v0, a); acc8(v1, a); acc8(v2, a); acc8(v3, a);
    }
    for (; j < j1; ++j) {
        uint4 v = g16[(size_t)esrc[j] * 16 + c];
        acc8(v, a);
    }
    float di = dinv[n];
    const float4* bp = reinterpret_cast<const float4*>(bias + c * 8);
    float4 b0 = bp[0], b1 = bp[1];
    float r0 = fmaf(a[0], di, b0.x), r1 = fmaf(a[1], di, b0.y);
    float r2 = fmaf(a[2], di, b0.z), r3 = fmaf(a[3], di, b0.w);
    float r4 = fmaf(a[4], di, b1.x), r5 = fmaf(a[5], di, b1.y);
    float r6 = fmaf(a[6], di, b1.z), r7 = fmaf(a[7], di, b1.w);
    uint4 o;
    o.x = (unsigned)f2b(r0) | ((unsigned)f2b(r1) << 16);
    o.y = (unsigned)f2b(r2) | ((unsigned)f2b(r3) << 16);
    o.z = (unsigned)f2b(r4) | ((unsigned)f2b(r5) << 16);
    o.w = (unsigned)f2b(r6) | ((unsigned)f2b(r7) << 16);
    out16[(size_t)n * 16 + c] = o;
}

// ---------------- mean pool (relu, bf16 input) ----------------
__global__ void k_pool(const unsigned short* __restrict__ B16, float* __restrict__ pooled) {
    int c = threadIdx.x;           // 0..127
    int r0 = blockIdx.x * 100;     // 1000 blocks * 100 rows
    float s = 0.f;
    for (int r = r0; r < r0 + 100; ++r) {
        float v = blo((unsigned int)B16[(size_t)r * DIM + c]);
        s += fmaxf(v, 0.f);
    }
    atomicAdd(&pooled[c], s);
}

// ---------------- fc + softmax ----------------
__global__ void k_final(const float* __restrict__ pooled, const float* __restrict__ fc_w,
                        const float* __restrict__ fc_b, float* __restrict__ out) {
    __shared__ float part[4][DIM];
    int c = threadIdx.x;  // 0..127
    float p = pooled[c] * (1.f / NN);
    for (int j = 0; j < 4; ++j) part[j][c] = p * fc_w[c * 4 + j];
    __syncthreads();
    if (c == 0) {
        float l[4];
        for (int j = 0; j < 4; ++j) {
            float s = fc_b[j];
            for (int i = 0; i < DIM; ++i) s += part[j][i];
            l[j] = s;
        }
        float m = fmaxf(fmaxf(l[0], l[1]), fmaxf(l[2], l[3]));
        float e[4], Z = 0.f;
        for (int j = 0; j < 4; ++j) { e[j] = expf(l[j] - m); Z += e[j]; }
        for (int j = 0; j < 4; ++j) out[j] = e[j] / Z;
    }
}

extern "C" void kernel_launch(void* const* d_in, const int* in_sizes, int n_in,
                              void* d_out, int out_size, void* d_ws, size_t ws_size,
                              hipStream_t stream) {
    const float* x   = (const float*)d_in[0];
    const int*   ei  = (const int*)d_in[1];
    const float* W1  = (const float*)d_in[2];
    const float* b1  = (const float*)d_in[3];
    const float* W2  = (const float*)d_in[4];
    const float* b2  = (const float*)d_in[5];
    const float* W3  = (const float*)d_in[6];
    const float* b3  = (const float*)d_in[7];
    const float* fcw = (const float*)d_in[8];
    const float* fcb = (const float*)d_in[9];
    float* out = (float*)d_out;

    char* ws = (char*)d_ws;
    void*  A16     = (void*)(ws);                   // 25,600,000 B (bf16 g)
    void*  B16     = (void*)(ws + 25600000);        // 25,600,000 B (bf16 act)
    float* dinv    = (float*)(ws + 51200000);       //    400,000 B
    int*   deg     = (int*)  (ws + 51600000);       //    400,000 B
    int*   rowptr  = (int*)  (ws + 52000000);       //    400,000 B
    int*   fillptr = (int*)  (ws + 52400000);       //    400,000 B
    int*   esrc    = (int*)  (ws + 52800000);       //  6,400,000 B
    int*   bsum    = (int*)  (ws + 59200000);       //        512 B
    int*   boff    = (int*)  (ws + 59201024);       //        512 B
    float* pooled  = (float*)(ws + 59202048);       //        512 B

    const int* src = ei;
    const int* dst = ei + NE;

    // ---- CSR build (once; reused across all 3 layers) ----
    k_zeroi<<<(NN + 255) / 256, 256, 0, stream>>>(deg, NN);
    k_counti<<<(NE + 255) / 256, 256, 0, stream>>>(dst, deg);
    k_dinv<<<(NN + 255) / 256, 256, 0, stream>>>(deg, dinv);
    k_scan1<<<SCAN_B, 1024, 0, stream>>>(deg, bsum);
    k_scan2<<<1, 64, 0, stream>>>(bsum, boff);
    k_scan3<<<SCAN_B, 1024, 0, stream>>>(deg, boff, rowptr, fillptr);
    k_fill<<<(NE + 255) / 256, 256, 0, stream>>>(src, dst, fillptr, esrc);
    // after k_fill, fillptr[n] == rowptr[n] + deg[n] == row end

    const int GB = (NN + 63) / 64;  // 1563
    // ---- layer 1 (fp32 input, no relu) ----
    k_gemm<true><<<GB, 256, 0, stream>>>(x, W1, dinv, (uint4*)A16);
    k_gather<<<NN * 16 / 256, 256, 0, stream>>>((const uint4*)A16, esrc, rowptr, fillptr, dinv, b1, (uint4*)B16);
    // ---- layer 2 ----
    k_gemm<false><<<GB, 256, 0, stream>>>(B16, W2, dinv, (uint4*)A16);
    k_gather<<<NN * 16 / 256, 256, 0, stream>>>((const uint4*)A16, esrc, rowptr, fillptr, dinv, b2, (uint4*)B16);
    // ---- layer 3 ----
    k_gemm<false><<<GB, 256, 0, stream>>>(B16, W3, dinv, (uint4*)A16);
    k_gather<<<NN * 16 / 256, 256, 0, stream>>>((const uint4*)A16, esrc, rowptr, fillptr, dinv, b3, (uint4*)B16);

    // ---- pool + fc + softmax ----
    k_zerof<<<1, 128, 0, stream>>>(pooled, DIM);
    k_pool<<<1000, 128, 0, stream>>>((const unsigned short*)B16, pooled);
    k_final<<<1, 128, 0, stream>>>(pooled, fcw, fcb, out);
}

// Round 5
// 341.680 us; speedup vs baseline: 24.7274x; 1.4350x over previous
//
#include <hip/hip_runtime.h>
#include <math.h>

#define NN 100000
#define NE 1600000
#define DIM 128
#define NBKT 196      // ceil(100000/512) coarse buckets (dst>>9)
#define PA_EPB 4096   // edges per passA block
#define PA_GRID ((NE + PA_EPB - 1) / PA_EPB)   // 391
#define PB_MAX 10240  // max edges per bucket (avg 8192, sigma ~90)

typedef __attribute__((ext_vector_type(8))) short short8;
typedef __attribute__((ext_vector_type(4))) float f32x4;

// ---- bf16 helpers (raw ushort) ----
__device__ __forceinline__ unsigned short f2b(float f) {   // RNE
    unsigned int b = __builtin_bit_cast(unsigned int, f);
    b += 0x7fffu + ((b >> 16) & 1u);
    return (unsigned short)(b >> 16);
}
__device__ __forceinline__ float blo(unsigned int u) { return __builtin_bit_cast(float, u << 16); }
__device__ __forceinline__ float bhi(unsigned int u) { return __builtin_bit_cast(float, u & 0xffff0000u); }
__device__ __forceinline__ unsigned int relu2(unsigned int v) {
    unsigned int keep = ((~v) & 0x80008000u) >> 15;
    return v & (keep * 0xffffu);
}
__device__ __forceinline__ void acc8(const uint4 v, float* a) {
    a[0] += blo(v.x); a[1] += bhi(v.x);
    a[2] += blo(v.y); a[3] += bhi(v.y);
    a[4] += blo(v.z); a[5] += bhi(v.z);
    a[6] += blo(v.w); a[7] += bhi(v.w);
}

// ---------------- zero helpers ----------------
__global__ void k_zerof(float* __restrict__ p, int n) {
    int i = blockIdx.x * blockDim.x + threadIdx.x;
    if (i < n) p[i] = 0.f;
}
__global__ void k_zeroi(int* __restrict__ p, int n) {
    int i = blockIdx.x * blockDim.x + threadIdx.x;
    if (i < n) p[i] = 0;
}

// ---------------- coarse histogram over dst buckets ----------------
__global__ __launch_bounds__(256) void k_hist(const int* __restrict__ dst,
                                              int* __restrict__ chist) {
    __shared__ int hist[NBKT];
    for (int i = threadIdx.x; i < NBKT; i += 256) hist[i] = 0;
    __syncthreads();
    int e0 = blockIdx.x * PA_EPB;
    int ecnt = min(PA_EPB, NE - e0);
    for (int i = threadIdx.x; i < ecnt; i += 256)
        atomicAdd(&hist[dst[e0 + i] >> 9], 1);
    __syncthreads();
    for (int i = threadIdx.x; i < NBKT; i += 256)
        if (hist[i]) atomicAdd(&chist[i], hist[i]);
}

// ---------------- scan of 196 bucket counts ----------------
__global__ __launch_bounds__(256) void k_scanb(const int* __restrict__ chist,
                                               int* __restrict__ cbase,
                                               int* __restrict__ gcursor) {
    __shared__ int sc[256];
    int tid = threadIdx.x;
    int v = (tid < NBKT) ? chist[tid] : 0;
    sc[tid] = v;
    __syncthreads();
    for (int off = 1; off < 256; off <<= 1) {
        int t = (tid >= off) ? sc[tid - off] : 0;
        __syncthreads();
        sc[tid] += t;
        __syncthreads();
    }
    if (tid < NBKT) {
        int ex = sc[tid] - v;
        cbase[tid] = ex;
        gcursor[tid] = ex;
    }
    if (tid == 0) cbase[NBKT] = NE;
}

// ---------------- passA: coarse partition into packed bucket-grouped array ----------------
// epk[i] = (local_dst<<17) | src, grouped by bucket (arbitrary order within bucket)
__global__ __launch_bounds__(256) void k_passA(const int* __restrict__ src,
                                               const int* __restrict__ dst,
                                               int* __restrict__ gcursor,
                                               unsigned int* __restrict__ epk) {
    __shared__ int hist[NBKT];
    __shared__ int offs[NBKT];
    __shared__ int gbase[NBKT];
    __shared__ int lcur[NBKT];
    __shared__ int sc[256];
    __shared__ unsigned int stg[PA_EPB];
    __shared__ unsigned char stgb[PA_EPB];
    const int tid = threadIdx.x;
    const int e0 = blockIdx.x * PA_EPB;
    const int ecnt = min(PA_EPB, NE - e0);

    for (int i = tid; i < NBKT; i += 256) hist[i] = 0;
    __syncthreads();
    for (int i = tid; i < ecnt; i += 256)
        atomicAdd(&hist[dst[e0 + i] >> 9], 1);
    __syncthreads();
    // exclusive scan hist -> offs
    int v = (tid < NBKT) ? hist[tid] : 0;
    sc[tid] = v;
    __syncthreads();
    for (int off = 1; off < 256; off <<= 1) {
        int t = (tid >= off) ? sc[tid - off] : 0;
        __syncthreads();
        sc[tid] += t;
        __syncthreads();
    }
    if (tid < NBKT) {
        offs[tid] = sc[tid] - v;
        lcur[tid] = sc[tid] - v;
        gbase[tid] = v ? atomicAdd(&gcursor[tid], v) : 0;
    }
    __syncthreads();
    // scatter into LDS staging, bucket-grouped
    for (int i = tid; i < ecnt; i += 256) {
        int d = dst[e0 + i];
        int s = src[e0 + i];
        int b = d >> 9;
        int pos = atomicAdd(&lcur[b], 1);
        stg[pos] = ((unsigned)(d & 511) << 17) | (unsigned)s;
        stgb[pos] = (unsigned char)b;
    }
    __syncthreads();
    // coalesced-run writeout
    for (int i = tid; i < ecnt; i += 256) {
        int b = stgb[i];
        epk[gbase[b] + (i - offs[b])] = stg[i];
    }
}

// ---------------- passB: per-bucket fine CSR + rowptr + dinv ----------------
__global__ __launch_bounds__(256) void k_passB(const unsigned int* __restrict__ epk,
                                               const int* __restrict__ cbase,
                                               int* __restrict__ rowptr,
                                               float* __restrict__ dinv,
                                               int* __restrict__ esrc) {
    __shared__ int cnt[512];
    __shared__ int offs[512];
    __shared__ int lcur[512];
    __shared__ int sc[256];
    __shared__ int stg[PB_MAX];
    const int b = blockIdx.x, tid = threadIdx.x;
    const int n0 = b << 9;
    const int nnb = min(512, NN - n0);
    const int ebase = cbase[b];
    const int ecnt = min(cbase[b + 1] - ebase, PB_MAX);

    for (int i = tid; i < 512; i += 256) cnt[i] = 0;
    __syncthreads();
    for (int i = tid; i < ecnt; i += 256)
        atomicAdd(&cnt[epk[ebase + i] >> 17], 1);
    __syncthreads();
    // exclusive scan of cnt[512]: 2 elems/thread
    int a0 = cnt[2 * tid], a1 = cnt[2 * tid + 1];
    sc[tid] = a0 + a1;
    __syncthreads();
    for (int off = 1; off < 256; off <<= 1) {
        int t = (tid >= off) ? sc[tid - off] : 0;
        __syncthreads();
        sc[tid] += t;
        __syncthreads();
    }
    int base = sc[tid] - (a0 + a1);
    offs[2 * tid] = base;
    offs[2 * tid + 1] = base + a0;
    lcur[2 * tid] = base;
    lcur[2 * tid + 1] = base + a0;
    __syncthreads();
    // rowptr / dinv (coalesced)
    for (int ln = tid; ln < nnb; ln += 256) {
        rowptr[n0 + ln] = ebase + offs[ln];
        dinv[n0 + ln] = rsqrtf(1.f + (float)cnt[ln]);
    }
    if (b == NBKT - 1 && tid == 0) rowptr[NN] = NE;
    // place srcs into LDS staging at scanned positions
    for (int i = tid; i < ecnt; i += 256) {
        unsigned p = epk[ebase + i];
        int pos = atomicAdd(&lcur[p >> 17], 1);
        stg[pos] = (int)(p & 0x1FFFFu);
    }
    __syncthreads();
    // stream out coalesced
    for (int i = tid; i < ecnt; i += 256)
        esrc[ebase + i] = stg[i];
}

// ------- MFMA transform: g[N,128](bf16) = (relu?)(in) @ W * dinv[row] -------
template <bool F32IN>
__global__ __launch_bounds__(256) void k_gemm(const void* __restrict__ inp,
                                              const float* __restrict__ W,
                                              const float* __restrict__ dinv,
                                              uint4* __restrict__ out16) {
    __shared__ short Wt[DIM * DIM];
    __shared__ short Xb[64 * DIM];
    const int tid = threadIdx.x;
    const int rb = blockIdx.x * 64;

    for (int idx = tid; idx < DIM * 16; idx += 256) {
        int c  = idx & 127;
        int kc = idx >> 7;
        uint4 p;
        p.x = (unsigned)f2b(W[(kc * 8 + 0) * DIM + c]) | ((unsigned)f2b(W[(kc * 8 + 1) * DIM + c]) << 16);
        p.y = (unsigned)f2b(W[(kc * 8 + 2) * DIM + c]) | ((unsigned)f2b(W[(kc * 8 + 3) * DIM + c]) << 16);
        p.z = (unsigned)f2b(W[(kc * 8 + 4) * DIM + c]) | ((unsigned)f2b(W[(kc * 8 + 5) * DIM + c]) << 16);
        p.w = (unsigned)f2b(W[(kc * 8 + 6) * DIM + c]) | ((unsigned)f2b(W[(kc * 8 + 7) * DIM + c]) << 16);
        int chunk = c * 16 + (kc ^ (c & 7));
        *reinterpret_cast<uint4*>(&Wt[chunk * 8]) = p;
    }
    for (int idx = tid; idx < 64 * 16; idx += 256) {
        int row = idx >> 4, kc = idx & 15;
        int grow = rb + row;
        uint4 p = make_uint4(0u, 0u, 0u, 0u);
        if (grow < NN) {
            if (F32IN) {
                const float* xp = (const float*)inp + (size_t)grow * DIM + kc * 8;
                p.x = (unsigned)f2b(xp[0]) | ((unsigned)f2b(xp[1]) << 16);
                p.y = (unsigned)f2b(xp[2]) | ((unsigned)f2b(xp[3]) << 16);
                p.z = (unsigned)f2b(xp[4]) | ((unsigned)f2b(xp[5]) << 16);
                p.w = (unsigned)f2b(xp[6]) | ((unsigned)f2b(xp[7]) << 16);
            } else {
                uint4 v = ((const uint4*)inp)[(size_t)grow * 16 + kc];
                p.x = relu2(v.x); p.y = relu2(v.y); p.z = relu2(v.z); p.w = relu2(v.w);
            }
        }
        int chunk = row * 16 + (kc ^ (row & 7));
        *reinterpret_cast<uint4*>(&Xb[chunk * 8]) = p;
    }
    __syncthreads();

    const int lane = tid & 63;
    const int w    = tid >> 6;
    const int l15  = lane & 15;
    const int kg   = lane >> 4;
    f32x4 acc[8];
#pragma unroll
    for (int i = 0; i < 8; ++i) acc[i] = (f32x4){0.f, 0.f, 0.f, 0.f};

    const int arow = w * 16 + l15;
#pragma unroll
    for (int ks = 0; ks < 4; ++ks) {
        int kc = ks * 4 + kg;
        short8 a = *reinterpret_cast<const short8*>(&Xb[(arow * 16 + (kc ^ (arow & 7))) * 8]);
#pragma unroll
        for (int ct = 0; ct < 8; ++ct) {
            int col = ct * 16 + l15;
            short8 bb = *reinterpret_cast<const short8*>(&Wt[(col * 16 + (kc ^ (col & 7))) * 8]);
            acc[ct] = __builtin_amdgcn_mfma_f32_16x16x32_bf16(a, bb, acc[ct], 0, 0, 0);
        }
    }
    __syncthreads();

    float dv[4];
#pragma unroll
    for (int reg = 0; reg < 4; ++reg) {
        int grow = rb + w * 16 + kg * 4 + reg;
        dv[reg] = (grow < NN) ? dinv[grow] : 0.f;
    }
#pragma unroll
    for (int ct = 0; ct < 8; ++ct) {
        int col = ct * 16 + l15;
#pragma unroll
        for (int reg = 0; reg < 4; ++reg) {
            int row = w * 16 + kg * 4 + reg;
            Xb[row * DIM + (((col >> 3) ^ (row & 7)) << 3) + (col & 7)] =
                (short)f2b(acc[ct][reg] * dv[reg]);
        }
    }
    __syncthreads();

    for (int idx = tid; idx < 64 * 16; idx += 256) {
        int row = idx >> 4, kc = idx & 15;
        int grow = rb + row;
        if (grow < NN)
            out16[(size_t)grow * 16 + kc] =
                *reinterpret_cast<const uint4*>(&Xb[(row * 16 + (kc ^ (row & 7))) * 8]);
    }
}

// ------- gather-reduce (bf16 rows): out[n] = dinv[n]*(g[n] + sum g[src]) + b -------
__global__ __launch_bounds__(256) void k_gather(const uint4* __restrict__ g16,
                                                const int* __restrict__ esrc,
                                                const int* __restrict__ rowptr,
                                                const int* __restrict__ rowend,
                                                const float* __restrict__ dinv,
                                                const float* __restrict__ bias,
                                                uint4* __restrict__ out16) {
    int t = blockIdx.x * 256 + threadIdx.x;
    int n = t >> 4;
    if (n >= NN) return;
    int c = t & 15;
    int j0 = rowptr[n], j1 = rowend[n];
    float a[8];
    uint4 sv = g16[(size_t)n * 16 + c];
    a[0] = blo(sv.x); a[1] = bhi(sv.x); a[2] = blo(sv.y); a[3] = bhi(sv.y);
    a[4] = blo(sv.z); a[5] = bhi(sv.z); a[6] = blo(sv.w); a[7] = bhi(sv.w);
    int j = j0;
    for (; j + 4 <= j1; j += 4) {
        int s0 = esrc[j], s1 = esrc[j + 1], s2 = esrc[j + 2], s3 = esrc[j + 3];
        uint4 v0 = g16[(size_t)s0 * 16 + c];
        uint4 v1 = g16[(size_t)s1 * 16 + c];
        uint4 v2 = g16[(size_t)s2 * 16 + c];
        uint4 v3 = g16[(size_t)s3 * 16 + c];
        acc8(v0, a); acc8(v1, a); acc8(v2, a); acc8(v3, a);
    }
    for (; j < j1; ++j) {
        uint4 v = g16[(size_t)esrc[j] * 16 + c];
        acc8(v, a);
    }
    float di = dinv[n];
    const float4* bp = reinterpret_cast<const float4*>(bias + c * 8);
    float4 b0 = bp[0], b1 = bp[1];
    float r0 = fmaf(a[0], di, b0.x), r1 = fmaf(a[1], di, b0.y);
    float r2 = fmaf(a[2], di, b0.z), r3 = fmaf(a[3], di, b0.w);
    float r4 = fmaf(a[4], di, b1.x), r5 = fmaf(a[5], di, b1.y);
    float r6 = fmaf(a[6], di, b1.z), r7 = fmaf(a[7], di, b1.w);
    uint4 o;
    o.x = (unsigned)f2b(r0) | ((unsigned)f2b(r1) << 16);
    o.y = (unsigned)f2b(r2) | ((unsigned)f2b(r3) << 16);
    o.z = (unsigned)f2b(r4) | ((unsigned)f2b(r5) << 16);
    o.w = (unsigned)f2b(r6) | ((unsigned)f2b(r7) << 16);
    out16[(size_t)n * 16 + c] = o;
}

// ---------------- mean pool (relu, bf16 input) ----------------
__global__ void k_pool(const unsigned short* __restrict__ B16, float* __restrict__ pooled) {
    int c = threadIdx.x;
    int r0 = blockIdx.x * 100;
    float s = 0.f;
    for (int r = r0; r < r0 + 100; ++r) {
        float v = blo((unsigned int)B16[(size_t)r * DIM + c]);
        s += fmaxf(v, 0.f);
    }
    atomicAdd(&pooled[c], s);
}

// ---------------- fc + softmax ----------------
__global__ void k_final(const float* __restrict__ pooled, const float* __restrict__ fc_w,
                        const float* __restrict__ fc_b, float* __restrict__ out) {
    __shared__ float part[4][DIM];
    int c = threadIdx.x;
    float p = pooled[c] * (1.f / NN);
    for (int j = 0; j < 4; ++j) part[j][c] = p * fc_w[c * 4 + j];
    __syncthreads();
    if (c == 0) {
        float l[4];
        for (int j = 0; j < 4; ++j) {
            float s = fc_b[j];
            for (int i = 0; i < DIM; ++i) s += part[j][i];
            l[j] = s;
        }
        float m = fmaxf(fmaxf(l[0], l[1]), fmaxf(l[2], l[3]));
        float e[4], Z = 0.f;
        for (int j = 0; j < 4; ++j) { e[j] = expf(l[j] - m); Z += e[j]; }
        for (int j = 0; j < 4; ++j) out[j] = e[j] / Z;
    }
}

extern "C" void kernel_launch(void* const* d_in, const int* in_sizes, int n_in,
                              void* d_out, int out_size, void* d_ws, size_t ws_size,
                              hipStream_t stream) {
    const float* x   = (const float*)d_in[0];
    const int*   ei  = (const int*)d_in[1];
    const float* W1  = (const float*)d_in[2];
    const float* b1  = (const float*)d_in[3];
    const float* W2  = (const float*)d_in[4];
    const float* b2  = (const float*)d_in[5];
    const float* W3  = (const float*)d_in[6];
    const float* b3  = (const float*)d_in[7];
    const float* fcw = (const float*)d_in[8];
    const float* fcb = (const float*)d_in[9];
    float* out = (float*)d_out;

    char* ws = (char*)d_ws;
    void*  A16     = (void*)(ws);                   // 25,600,000 B
    void*  B16     = (void*)(ws + 25600000);        // 25,600,000 B
    float* dinv    = (float*)(ws + 51200000);       //    400,000 B
    int*   rowptr  = (int*)  (ws + 51600000);       //    400,128 B (NN+1)
    int*   esrc    = (int*)  (ws + 52000128);       //  6,400,000 B
    unsigned int* epk = (unsigned int*)(ws + 58400128);  // 6,400,000 B
    int*   chist   = (int*)  (ws + 64800128);       //      1,024 B
    int*   cbase   = (int*)  (ws + 64801152);       //      1,024 B
    int*   gcursor = (int*)  (ws + 64802176);       //      1,024 B
    float* pooled  = (float*)(ws + 64803200);       //        512 B

    const int* src = ei;
    const int* dst = ei + NE;

    // ---- CSR build: two-level LDS-binned partition ----
    k_zeroi<<<1, 256, 0, stream>>>(chist, NBKT);
    k_hist<<<PA_GRID, 256, 0, stream>>>(dst, chist);
    k_scanb<<<1, 256, 0, stream>>>(chist, cbase, gcursor);
    k_passA<<<PA_GRID, 256, 0, stream>>>(src, dst, gcursor, epk);
    k_passB<<<NBKT, 256, 0, stream>>>(epk, cbase, rowptr, dinv, esrc);

    const int GB = (NN + 63) / 64;  // 1563
    // ---- layer 1 ----
    k_gemm<true><<<GB, 256, 0, stream>>>(x, W1, dinv, (uint4*)A16);
    k_gather<<<NN * 16 / 256, 256, 0, stream>>>((const uint4*)A16, esrc, rowptr, rowptr + 1, dinv, b1, (uint4*)B16);
    // ---- layer 2 ----
    k_gemm<false><<<GB, 256, 0, stream>>>(B16, W2, dinv, (uint4*)A16);
    k_gather<<<NN * 16 / 256, 256, 0, stream>>>((const uint4*)A16, esrc, rowptr, rowptr + 1, dinv, b2, (uint4*)B16);
    // ---- layer 3 ----
    k_gemm<false><<<GB, 256, 0, stream>>>(B16, W3, dinv, (uint4*)A16);
    k_gather<<<NN * 16 / 256, 256, 0, stream>>>((const uint4*)A16, esrc, rowptr, rowptr + 1, dinv, b3, (uint4*)B16);

    // ---- pool + fc + softmax ----
    k_zerof<<<1, 128, 0, stream>>>(pooled, DIM);
    k_pool<<<1000, 128, 0, stream>>>((const unsigned short*)B16, pooled);
    k_final<<<1, 128, 0, stream>>>(pooled, fcw, fcb, out);
}

// Round 6
// 336.865 us; speedup vs baseline: 25.0809x; 1.0143x over previous
//
#include <hip/hip_runtime.h>
#include <math.h>

#define NN 100000
#define NE 1600000
#define DIM 128
#define NBKT 196        // ceil(100000/512) coarse buckets (dst>>9)
#define BSTRIDE 9216    // per-bucket arena stride (mean 8192 + 11 sigma)
#define PA_EPB 4096
#define PA_GRID ((NE + PA_EPB - 1) / PA_EPB)   // 391
#define NPOOLB 6250     // gather grid (NN*16/256)

typedef __attribute__((ext_vector_type(8))) short short8;
typedef __attribute__((ext_vector_type(4))) float f32x4;

// ---- bf16 helpers (raw ushort) ----
__device__ __forceinline__ unsigned int f2b(float f) {   // RNE -> low 16 bits
    unsigned int b = __builtin_bit_cast(unsigned int, f);
    b += 0x7fffu + ((b >> 16) & 1u);
    return b >> 16;
}
__device__ __forceinline__ float blo(unsigned int u) { return __builtin_bit_cast(float, u << 16); }
__device__ __forceinline__ float bhi(unsigned int u) { return __builtin_bit_cast(float, u & 0xffff0000u); }
__device__ __forceinline__ unsigned int relu2(unsigned int v) {
    unsigned int keep = ((~v) & 0x80008000u) >> 15;
    return v & (keep * 0xffffu);
}
__device__ __forceinline__ void acc8(const uint4 v, float* a) {
    a[0] += blo(v.x); a[1] += bhi(v.x);
    a[2] += blo(v.y); a[3] += bhi(v.y);
    a[4] += blo(v.z); a[5] += bhi(v.z);
    a[6] += blo(v.w); a[7] += bhi(v.w);
}

// ---------------- init arena cursors ----------------
__global__ void k_initcur(int* __restrict__ gcursor) {
    int i = threadIdx.x;
    if (i < NBKT) gcursor[i] = i * BSTRIDE;
}

// ---------------- passA: coarse partition into per-bucket arenas ----------------
// epk[i] = (local_dst<<17) | src  (src < 2^17)
__global__ __launch_bounds__(256) void k_passA(const int* __restrict__ src,
                                               const int* __restrict__ dst,
                                               int* __restrict__ gcursor,
                                               unsigned int* __restrict__ epk) {
    __shared__ int hist[NBKT];
    __shared__ int offs[NBKT];
    __shared__ int gbase[NBKT];
    __shared__ int lcur[NBKT];
    __shared__ int sc[256];
    __shared__ unsigned int stg[PA_EPB];
    __shared__ unsigned char stgb[PA_EPB];
    const int tid = threadIdx.x;
    const int e0 = blockIdx.x * PA_EPB;
    const int ecnt = min(PA_EPB, NE - e0);

    for (int i = tid; i < NBKT; i += 256) hist[i] = 0;
    __syncthreads();
    for (int i = tid; i < ecnt; i += 256)
        atomicAdd(&hist[dst[e0 + i] >> 9], 1);
    __syncthreads();
    int v = (tid < NBKT) ? hist[tid] : 0;
    sc[tid] = v;
    __syncthreads();
    for (int off = 1; off < 256; off <<= 1) {
        int t = (tid >= off) ? sc[tid - off] : 0;
        __syncthreads();
        sc[tid] += t;
        __syncthreads();
    }
    if (tid < NBKT) {
        offs[tid] = sc[tid] - v;
        lcur[tid] = sc[tid] - v;
        gbase[tid] = v ? atomicAdd(&gcursor[tid], v) : 0;
    }
    __syncthreads();
    for (int i = tid; i < ecnt; i += 256) {
        int d = dst[e0 + i];
        int s = src[e0 + i];
        int b = d >> 9;
        int pos = atomicAdd(&lcur[b], 1);
        stg[pos] = ((unsigned)(d & 511) << 17) | (unsigned)s;
        stgb[pos] = (unsigned char)b;
    }
    __syncthreads();
    for (int i = tid; i < ecnt; i += 256) {
        int b = stgb[i];
        epk[gbase[b] + (i - offs[b])] = stg[i];
    }
}

// ---------------- passB: per-bucket fine CSR + rowptr/dinv + degree-sorted order ----------------
__global__ __launch_bounds__(256) void k_passB(const unsigned int* __restrict__ epk,
                                               const int* __restrict__ gcursor,
                                               int* __restrict__ rowptr,
                                               float* __restrict__ dinv,
                                               int* __restrict__ esrc,
                                               unsigned int* __restrict__ nodeord) {
    __shared__ int cnt[512];
    __shared__ int offs[512];
    __shared__ int lcur[512];
    __shared__ int sc[256];
    __shared__ int stg[BSTRIDE];
    __shared__ int dhist[64], dbase[64], dcur[64];
    const int b = blockIdx.x, tid = threadIdx.x;
    const int n0 = b << 9;
    const int nnb = min(512, NN - n0);
    const int ebase = b * BSTRIDE;
    const int ecnt = min(gcursor[b] - ebase, BSTRIDE);

    for (int i = tid; i < 512; i += 256) cnt[i] = 0;
    if (tid < 64) dhist[tid] = 0;
    __syncthreads();
    for (int i = tid; i < ecnt; i += 256)
        atomicAdd(&cnt[epk[ebase + i] >> 17], 1);
    __syncthreads();
    // exclusive scan of cnt[512]
    int a0 = cnt[2 * tid], a1 = cnt[2 * tid + 1];
    sc[tid] = a0 + a1;
    __syncthreads();
    for (int off = 1; off < 256; off <<= 1) {
        int t = (tid >= off) ? sc[tid - off] : 0;
        __syncthreads();
        sc[tid] += t;
        __syncthreads();
    }
    int base = sc[tid] - (a0 + a1);
    offs[2 * tid] = base;
    offs[2 * tid + 1] = base + a0;
    lcur[2 * tid] = base;
    lcur[2 * tid + 1] = base + a0;
    __syncthreads();
    // rowptr / dinv / degree histogram
    for (int ln = tid; ln < nnb; ln += 256) {
        int dg = cnt[ln];
        rowptr[n0 + ln] = ebase + offs[ln];
        dinv[n0 + ln] = rsqrtf(1.f + (float)dg);
        atomicAdd(&dhist[min(dg, 63)], 1);
    }
    __syncthreads();
    if (tid == 0) {
        int acc = 0;
        for (int d = 0; d < 64; ++d) { dbase[d] = acc; dcur[d] = acc; acc += dhist[d]; }
    }
    __syncthreads();
    // degree-sorted node order (within bucket)
    for (int ln = tid; ln < nnb; ln += 256) {
        int dg = cnt[ln];
        int rank = atomicAdd(&dcur[min(dg, 63)], 1);
        nodeord[n0 + rank] = ((unsigned)dg << 17) | (unsigned)(n0 + ln);
    }
    // place srcs at scanned positions
    for (int i = tid; i < ecnt; i += 256) {
        unsigned p = epk[ebase + i];
        int pos = atomicAdd(&lcur[p >> 17], 1);
        stg[pos] = (int)(p & 0x1FFFFu);
    }
    __syncthreads();
    for (int i = tid; i < ecnt; i += 256)
        esrc[ebase + i] = stg[i];
}

// ---------------- W pre-convert: fp32 [k][c] -> bf16 swizzled LDS image ----------------
__global__ void k_wcvt(const float* __restrict__ W1, const float* __restrict__ W2,
                       const float* __restrict__ W3, uint4* __restrict__ Wg) {
    int t = blockIdx.x * 256 + threadIdx.x;
    if (t >= 3 * 2048) return;
    int layer = t >> 11, idx = t & 2047;
    const float* W = layer == 0 ? W1 : (layer == 1 ? W2 : W3);
    int c = idx >> 4;    // 0..127
    int kc = idx & 15;   // 0..15
    uint4 p;
    p.x = f2b(W[(kc * 8 + 0) * DIM + c]) | (f2b(W[(kc * 8 + 1) * DIM + c]) << 16);
    p.y = f2b(W[(kc * 8 + 2) * DIM + c]) | (f2b(W[(kc * 8 + 3) * DIM + c]) << 16);
    p.z = f2b(W[(kc * 8 + 4) * DIM + c]) | (f2b(W[(kc * 8 + 5) * DIM + c]) << 16);
    p.w = f2b(W[(kc * 8 + 6) * DIM + c]) | (f2b(W[(kc * 8 + 7) * DIM + c]) << 16);
    int chunk = c * 16 + (kc ^ (c & 7));
    Wg[layer * 2048 + chunk] = p;
}

// ------- MFMA transform: g[N,128](bf16) = (relu?)(in) @ W * dinv[row] -------
template <bool F32IN>
__global__ __launch_bounds__(256) void k_gemm(const void* __restrict__ inp,
                                              const uint4* __restrict__ Wg,
                                              const float* __restrict__ dinv,
                                              uint4* __restrict__ out16) {
    __shared__ short Wt[DIM * DIM];
    __shared__ short Xb[64 * DIM];
    const int tid = threadIdx.x;
    const int rb = blockIdx.x * 64;

    for (int idx = tid; idx < 2048; idx += 256)
        reinterpret_cast<uint4*>(Wt)[idx] = Wg[idx];
    for (int idx = tid; idx < 64 * 16; idx += 256) {
        int row = idx >> 4, kc = idx & 15;
        int grow = rb + row;
        uint4 p = make_uint4(0u, 0u, 0u, 0u);
        if (grow < NN) {
            if (F32IN) {
                const float* xp = (const float*)inp + (size_t)grow * DIM + kc * 8;
                p.x = f2b(xp[0]) | (f2b(xp[1]) << 16);
                p.y = f2b(xp[2]) | (f2b(xp[3]) << 16);
                p.z = f2b(xp[4]) | (f2b(xp[5]) << 16);
                p.w = f2b(xp[6]) | (f2b(xp[7]) << 16);
            } else {
                uint4 v = ((const uint4*)inp)[(size_t)grow * 16 + kc];
                p.x = relu2(v.x); p.y = relu2(v.y); p.z = relu2(v.z); p.w = relu2(v.w);
            }
        }
        int chunk = row * 16 + (kc ^ (row & 7));
        *reinterpret_cast<uint4*>(&Xb[chunk * 8]) = p;
    }
    __syncthreads();

    const int lane = tid & 63;
    const int w    = tid >> 6;
    const int l15  = lane & 15;
    const int kg   = lane >> 4;
    f32x4 acc[8];
#pragma unroll
    for (int i = 0; i < 8; ++i) acc[i] = (f32x4){0.f, 0.f, 0.f, 0.f};

    const int arow = w * 16 + l15;
#pragma unroll
    for (int ks = 0; ks < 4; ++ks) {
        int kc = ks * 4 + kg;
        short8 a = *reinterpret_cast<const short8*>(&Xb[(arow * 16 + (kc ^ (arow & 7))) * 8]);
#pragma unroll
        for (int ct = 0; ct < 8; ++ct) {
            int col = ct * 16 + l15;
            short8 bb = *reinterpret_cast<const short8*>(&Wt[(col * 16 + (kc ^ (col & 7))) * 8]);
            acc[ct] = __builtin_amdgcn_mfma_f32_16x16x32_bf16(a, bb, acc[ct], 0, 0, 0);
        }
    }
    __syncthreads();

    float dv[4];
#pragma unroll
    for (int reg = 0; reg < 4; ++reg) {
        int grow = rb + w * 16 + kg * 4 + reg;
        dv[reg] = (grow < NN) ? dinv[grow] : 0.f;
    }
#pragma unroll
    for (int ct = 0; ct < 8; ++ct) {
        int col = ct * 16 + l15;
#pragma unroll
        for (int reg = 0; reg < 4; ++reg) {
            int row = w * 16 + kg * 4 + reg;
            Xb[row * DIM + (((col >> 3) ^ (row & 7)) << 3) + (col & 7)] =
                (short)f2b(acc[ct][reg] * dv[reg]);
        }
    }
    __syncthreads();

    for (int idx = tid; idx < 64 * 16; idx += 256) {
        int row = idx >> 4, kc = idx & 15;
        int grow = rb + row;
        if (grow < NN)
            out16[(size_t)grow * 16 + kc] =
                *reinterpret_cast<const uint4*>(&Xb[(row * 16 + (kc ^ (row & 7))) * 8]);
    }
}

// ------- gather-reduce, degree-sorted; POOL variant fuses relu + mean-pool partials -------
template <bool POOL>
__global__ __launch_bounds__(256) void k_gather(const uint4* __restrict__ g16,
                                                const int* __restrict__ esrc,
                                                const int* __restrict__ rowptr,
                                                const unsigned int* __restrict__ nodeord,
                                                const float* __restrict__ dinv,
                                                const float* __restrict__ bias,
                                                uint4* __restrict__ out16,
                                                float* __restrict__ ppart) {
    int t = blockIdx.x * 256 + threadIdx.x;
    int idx = t >> 4;
    int c = t & 15;
    unsigned po = nodeord[idx];
    int n = (int)(po & 0x1FFFFu);
    int dg = (int)(po >> 17);
    int j0 = rowptr[n], j1 = j0 + dg;
    float a[8];
    uint4 sv = g16[(size_t)n * 16 + c];
    a[0] = blo(sv.x); a[1] = bhi(sv.x); a[2] = blo(sv.y); a[3] = bhi(sv.y);
    a[4] = blo(sv.z); a[5] = bhi(sv.z); a[6] = blo(sv.w); a[7] = bhi(sv.w);
    int j = j0;
    for (; j + 4 <= j1; j += 4) {
        int s0 = esrc[j], s1 = esrc[j + 1], s2 = esrc[j + 2], s3 = esrc[j + 3];
        uint4 v0 = g16[(size_t)s0 * 16 + c];
        uint4 v1 = g16[(size_t)s1 * 16 + c];
        uint4 v2 = g16[(size_t)s2 * 16 + c];
        uint4 v3 = g16[(size_t)s3 * 16 + c];
        acc8(v0, a); acc8(v1, a); acc8(v2, a); acc8(v3, a);
    }
    for (; j < j1; ++j) {
        uint4 v = g16[(size_t)esrc[j] * 16 + c];
        acc8(v, a);
    }
    float di = dinv[n];
    const float4* bp = reinterpret_cast<const float4*>(bias + c * 8);
    float4 b0 = bp[0], b1 = bp[1];
    float r[8];
    r[0] = fmaf(a[0], di, b0.x); r[1] = fmaf(a[1], di, b0.y);
    r[2] = fmaf(a[2], di, b0.z); r[3] = fmaf(a[3], di, b0.w);
    r[4] = fmaf(a[4], di, b1.x); r[5] = fmaf(a[5], di, b1.y);
    r[6] = fmaf(a[6], di, b1.z); r[7] = fmaf(a[7], di, b1.w);
    if (!POOL) {
        uint4 o;
        o.x = f2b(r[0]) | (f2b(r[1]) << 16);
        o.y = f2b(r[2]) | (f2b(r[3]) << 16);
        o.z = f2b(r[4]) | (f2b(r[5]) << 16);
        o.w = f2b(r[6]) | (f2b(r[7]) << 16);
        out16[(size_t)n * 16 + c] = o;
    } else {
        __shared__ float red[16][132];
        int slot = threadIdx.x >> 4;
#pragma unroll
        for (int k = 0; k < 8; ++k)
            red[slot][c * 8 + k] = fmaxf(r[k], 0.f);
        __syncthreads();
        if (threadIdx.x < 128) {
            float s = 0.f;
#pragma unroll
            for (int sl = 0; sl < 16; ++sl) s += red[sl][threadIdx.x];
            ppart[blockIdx.x * 128 + threadIdx.x] = s;
        }
    }
}

// ---------------- pool partial reduce: 6250x128 -> 128x128 ----------------
__global__ void k_red1(const float* __restrict__ ppart, float* __restrict__ pp2) {
    int j = blockIdx.x;       // 0..127
    int c = threadIdx.x;      // 0..127
    int p0 = j * 49, p1 = min(p0 + 49, NPOOLB);
    float s = 0.f;
    for (int p = p0; p < p1; ++p) s += ppart[p * 128 + c];
    pp2[j * 128 + c] = s;
}

// ---------------- final: reduce 128x128 + fc + softmax ----------------
__global__ void k_final(const float* __restrict__ pp2, const float* __restrict__ fc_w,
                        const float* __restrict__ fc_b, float* __restrict__ out) {
    __shared__ float part[4][DIM];
    int c = threadIdx.x;  // 0..127
    float s = 0.f;
    for (int j = 0; j < 128; ++j) s += pp2[j * 128 + c];
    float p = s * (1.f / NN);
    for (int j = 0; j < 4; ++j) part[j][c] = p * fc_w[c * 4 + j];
    __syncthreads();
    if (c == 0) {
        float l[4];
        for (int j = 0; j < 4; ++j) {
            float acc = fc_b[j];
            for (int i = 0; i < DIM; ++i) acc += part[j][i];
            l[j] = acc;
        }
        float m = fmaxf(fmaxf(l[0], l[1]), fmaxf(l[2], l[3]));
        float e[4], Z = 0.f;
        for (int j = 0; j < 4; ++j) { e[j] = expf(l[j] - m); Z += e[j]; }
        for (int j = 0; j < 4; ++j) out[j] = e[j] / Z;
    }
}

extern "C" void kernel_launch(void* const* d_in, const int* in_sizes, int n_in,
                              void* d_out, int out_size, void* d_ws, size_t ws_size,
                              hipStream_t stream) {
    const float* x   = (const float*)d_in[0];
    const int*   ei  = (const int*)d_in[1];
    const float* W1  = (const float*)d_in[2];
    const float* b1  = (const float*)d_in[3];
    const float* W2  = (const float*)d_in[4];
    const float* b2  = (const float*)d_in[5];
    const float* W3  = (const float*)d_in[6];
    const float* b3  = (const float*)d_in[7];
    const float* fcw = (const float*)d_in[8];
    const float* fcb = (const float*)d_in[9];
    float* out = (float*)d_out;

    char* ws = (char*)d_ws;
    void*  A16     = (void*)(ws);                        // 25,600,000 B
    void*  B16     = (void*)(ws + 25600000);             // 25,600,000 B
    float* dinv    = (float*)(ws + 51200000);            //    400,000 B
    int*   rowptr  = (int*)  (ws + 51600000);            //    400,000 B
    unsigned int* nodeord = (unsigned int*)(ws + 52000000); // 400,000 B
    int*   esrc    = (int*)  (ws + 52400000);            //  7,225,344 B (196*9216*4)
    unsigned int* epk = (unsigned int*)(ws + 59625344);  //  7,225,344 B
    int*   gcursor = (int*)  (ws + 66850688);            //      1,024 B
    float* ppart   = (float*)(ws + 66851712);            //  3,200,000 B (6250*128)
    float* pp2     = (float*)(ws + 70051712);            //     65,536 B
    uint4* Wg      = (uint4*)(ws + 70117248);            //     98,304 B (3*2048*16)

    const int* src = ei;
    const int* dst = ei + NE;

    // ---- CSR build: single-pass arena partition ----
    k_initcur<<<1, 256, 0, stream>>>(gcursor);
    k_passA<<<PA_GRID, 256, 0, stream>>>(src, dst, gcursor, epk);
    k_passB<<<NBKT, 256, 0, stream>>>(epk, gcursor, rowptr, dinv, esrc, nodeord);
    k_wcvt<<<24, 256, 0, stream>>>(W1, W2, W3, Wg);

    const int GB = (NN + 63) / 64;  // 1563
    // ---- layer 1 ----
    k_gemm<true><<<GB, 256, 0, stream>>>(x, Wg, dinv, (uint4*)A16);
    k_gather<false><<<NPOOLB, 256, 0, stream>>>((const uint4*)A16, esrc, rowptr, nodeord, dinv, b1, (uint4*)B16, nullptr);
    // ---- layer 2 ----
    k_gemm<false><<<GB, 256, 0, stream>>>(B16, Wg + 2048, dinv, (uint4*)A16);
    k_gather<false><<<NPOOLB, 256, 0, stream>>>((const uint4*)A16, esrc, rowptr, nodeord, dinv, b2, (uint4*)B16, nullptr);
    // ---- layer 3 (fused relu + pool partials) ----
    k_gemm<false><<<GB, 256, 0, stream>>>(B16, Wg + 4096, dinv, (uint4*)A16);
    k_gather<true><<<NPOOLB, 256, 0, stream>>>((const uint4*)A16, esrc, rowptr, nodeord, dinv, b3, nullptr, ppart);

    // ---- pool reduce + fc + softmax ----
    k_red1<<<128, 128, 0, stream>>>(ppart, pp2);
    k_final<<<1, 128, 0, stream>>>(pp2, fcw, fcb, out);
}

// Round 7
// 219.433 us; speedup vs baseline: 38.5031x; 1.5352x over previous
//
#include <hip/hip_runtime.h>
#include <math.h>

#define NN 100000
#define NE 1600000
#define DIM 128
#define NBKT 196        // ceil(100000/512) coarse buckets (dst>>9)
#define BSTRIDE 9216    // per-bucket arena stride (mean 8192 + 11 sigma)
#define PA_EPB 4096
#define PA_GRID ((NE + PA_EPB - 1) / PA_EPB)   // 391
#define NGATB 3125      // gather grid: NN*8/256

typedef __attribute__((ext_vector_type(8))) short short8;
typedef __attribute__((ext_vector_type(4))) float f32x4;
typedef __attribute__((ext_vector_type(2))) float f32x2;

// ---- bf16 helpers (raw ushort) ----
__device__ __forceinline__ unsigned int f2b(float f) {   // RNE -> low 16 bits
    unsigned int b = __builtin_bit_cast(unsigned int, f);
    b += 0x7fffu + ((b >> 16) & 1u);
    return b >> 16;
}
__device__ __forceinline__ unsigned int relu2(unsigned int v) {
    unsigned int keep = ((~v) & 0x80008000u) >> 15;
    return v & (keep * 0xffffu);
}
// ---- fp8 e4m3 accumulate: 4 fp8 in a dword -> 4 float adds ----
__device__ __forceinline__ void accp8(unsigned int w, float* a) {
    f32x2 lo = __builtin_amdgcn_cvt_pk_f32_fp8(w, false);
    f32x2 hi = __builtin_amdgcn_cvt_pk_f32_fp8(w, true);
    a[0] += lo[0]; a[1] += lo[1]; a[2] += hi[0]; a[3] += hi[1];
}

// ---------------- init arena cursors ----------------
__global__ void k_initcur(int* __restrict__ gcursor) {
    int i = threadIdx.x;
    if (i < NBKT) gcursor[i] = i * BSTRIDE;
}

// ---------------- passA: coarse partition into per-bucket arenas ----------------
// epk[i] = (local_dst<<17) | src  (src < 2^17)
__global__ __launch_bounds__(256) void k_passA(const int* __restrict__ src,
                                               const int* __restrict__ dst,
                                               int* __restrict__ gcursor,
                                               unsigned int* __restrict__ epk) {
    __shared__ int hist[NBKT];
    __shared__ int offs[NBKT];
    __shared__ int gbase[NBKT];
    __shared__ int lcur[NBKT];
    __shared__ int sc[256];
    __shared__ unsigned int stg[PA_EPB];
    __shared__ unsigned char stgb[PA_EPB];
    const int tid = threadIdx.x;
    const int e0 = blockIdx.x * PA_EPB;
    const int ecnt = min(PA_EPB, NE - e0);

    for (int i = tid; i < NBKT; i += 256) hist[i] = 0;
    __syncthreads();
    for (int i = tid; i < ecnt; i += 256)
        atomicAdd(&hist[dst[e0 + i] >> 9], 1);
    __syncthreads();
    int v = (tid < NBKT) ? hist[tid] : 0;
    sc[tid] = v;
    __syncthreads();
    for (int off = 1; off < 256; off <<= 1) {
        int t = (tid >= off) ? sc[tid - off] : 0;
        __syncthreads();
        sc[tid] += t;
        __syncthreads();
    }
    if (tid < NBKT) {
        offs[tid] = sc[tid] - v;
        lcur[tid] = sc[tid] - v;
        gbase[tid] = v ? atomicAdd(&gcursor[tid], v) : 0;
    }
    __syncthreads();
    for (int i = tid; i < ecnt; i += 256) {
        int d = dst[e0 + i];
        int s = src[e0 + i];
        int b = d >> 9;
        int pos = atomicAdd(&lcur[b], 1);
        stg[pos] = ((unsigned)(d & 511) << 17) | (unsigned)s;
        stgb[pos] = (unsigned char)b;
    }
    __syncthreads();
    for (int i = tid; i < ecnt; i += 256) {
        int b = stgb[i];
        epk[gbase[b] + (i - offs[b])] = stg[i];
    }
}

// ---------------- passB: per-bucket fine CSR + rowptr/dinv/deg ----------------
__global__ __launch_bounds__(256) void k_passB(const unsigned int* __restrict__ epk,
                                               const int* __restrict__ gcursor,
                                               int* __restrict__ rowptr,
                                               float* __restrict__ dinv,
                                               int* __restrict__ degp,
                                               int* __restrict__ esrc) {
    __shared__ int cnt[512];
    __shared__ int offs[512];
    __shared__ int lcur[512];
    __shared__ int sc[256];
    __shared__ int stg[BSTRIDE];
    const int b = blockIdx.x, tid = threadIdx.x;
    const int n0 = b << 9;
    const int nnb = min(512, NN - n0);
    const int ebase = b * BSTRIDE;
    const int ecnt = min(gcursor[b] - ebase, BSTRIDE);

    for (int i = tid; i < 512; i += 256) cnt[i] = 0;
    __syncthreads();
    for (int i = tid; i < ecnt; i += 256)
        atomicAdd(&cnt[epk[ebase + i] >> 17], 1);
    __syncthreads();
    // exclusive scan of cnt[512]
    int a0 = cnt[2 * tid], a1 = cnt[2 * tid + 1];
    sc[tid] = a0 + a1;
    __syncthreads();
    for (int off = 1; off < 256; off <<= 1) {
        int t = (tid >= off) ? sc[tid - off] : 0;
        __syncthreads();
        sc[tid] += t;
        __syncthreads();
    }
    int base = sc[tid] - (a0 + a1);
    offs[2 * tid] = base;
    offs[2 * tid + 1] = base + a0;
    lcur[2 * tid] = base;
    lcur[2 * tid + 1] = base + a0;
    __syncthreads();
    for (int ln = tid; ln < nnb; ln += 256) {
        int dg = cnt[ln];
        rowptr[n0 + ln] = ebase + offs[ln];
        degp[n0 + ln] = dg;
        dinv[n0 + ln] = rsqrtf(1.f + (float)dg);
    }
    for (int i = tid; i < ecnt; i += 256) {
        unsigned p = epk[ebase + i];
        int pos = atomicAdd(&lcur[p >> 17], 1);
        stg[pos] = (int)(p & 0x1FFFFu);
    }
    __syncthreads();
    for (int i = tid; i < ecnt; i += 256)
        esrc[ebase + i] = stg[i];
}

// ---------------- W pre-convert: fp32 [k][c] -> bf16 swizzled LDS image ----------------
__global__ void k_wcvt(const float* __restrict__ W1, const float* __restrict__ W2,
                       const float* __restrict__ W3, uint4* __restrict__ Wg) {
    int t = blockIdx.x * 256 + threadIdx.x;
    if (t >= 3 * 2048) return;
    int layer = t >> 11, idx = t & 2047;
    const float* W = layer == 0 ? W1 : (layer == 1 ? W2 : W3);
    int c = idx >> 4;    // 0..127
    int kc = idx & 15;   // 0..15
    uint4 p;
    p.x = f2b(W[(kc * 8 + 0) * DIM + c]) | (f2b(W[(kc * 8 + 1) * DIM + c]) << 16);
    p.y = f2b(W[(kc * 8 + 2) * DIM + c]) | (f2b(W[(kc * 8 + 3) * DIM + c]) << 16);
    p.z = f2b(W[(kc * 8 + 4) * DIM + c]) | (f2b(W[(kc * 8 + 5) * DIM + c]) << 16);
    p.w = f2b(W[(kc * 8 + 6) * DIM + c]) | (f2b(W[(kc * 8 + 7) * DIM + c]) << 16);
    int chunk = c * 16 + (kc ^ (c & 7));
    Wg[layer * 2048 + chunk] = p;
}

// ------- MFMA transform: g[N,128](fp8) = ((relu?)(in) @ W) * dinv[row] -------
// Swapped-operand MFMA: acc = mfma(W-frag, X-frag) => C'[wcol][node];
// lane owns 4 consecutive wcols per tile -> in-register fp8 dword pack.
template <bool F32IN>
__global__ __launch_bounds__(256) void k_gemm(const void* __restrict__ inp,
                                              const uint4* __restrict__ Wg,
                                              const float* __restrict__ dinv,
                                              uint4* __restrict__ out8) {
    __shared__ short Wt[DIM * DIM];   // 32 KB
    __shared__ short Xb[64 * DIM];    // 16 KB, reused as fp8 out stage (8 KB)
    const int tid = threadIdx.x;
    const int rb = blockIdx.x * 64;

    for (int idx = tid; idx < 2048; idx += 256)
        reinterpret_cast<uint4*>(Wt)[idx] = Wg[idx];
    for (int idx = tid; idx < 64 * 16; idx += 256) {
        int row = idx >> 4, kc = idx & 15;
        int grow = rb + row;
        uint4 p = make_uint4(0u, 0u, 0u, 0u);
        if (grow < NN) {
            if (F32IN) {
                const float* xp = (const float*)inp + (size_t)grow * DIM + kc * 8;
                p.x = f2b(xp[0]) | (f2b(xp[1]) << 16);
                p.y = f2b(xp[2]) | (f2b(xp[3]) << 16);
                p.z = f2b(xp[4]) | (f2b(xp[5]) << 16);
                p.w = f2b(xp[6]) | (f2b(xp[7]) << 16);
            } else {
                uint4 v = ((const uint4*)inp)[(size_t)grow * 16 + kc];
                p.x = relu2(v.x); p.y = relu2(v.y); p.z = relu2(v.z); p.w = relu2(v.w);
            }
        }
        int chunk = row * 16 + (kc ^ (row & 7));
        *reinterpret_cast<uint4*>(&Xb[chunk * 8]) = p;
    }
    __syncthreads();

    const int lane = tid & 63;
    const int w    = tid >> 6;     // wave -> nodes w*16..w*16+15
    const int l15  = lane & 15;
    const int kg   = lane >> 4;    // 0..3
    f32x4 acc[8];
#pragma unroll
    for (int i = 0; i < 8; ++i) acc[i] = (f32x4){0.f, 0.f, 0.f, 0.f};

    const int arow = w * 16 + l15;  // node row for the X fragment
#pragma unroll
    for (int ks = 0; ks < 4; ++ks) {
        int kc = ks * 4 + kg;
        short8 xf = *reinterpret_cast<const short8*>(&Xb[(arow * 16 + (kc ^ (arow & 7))) * 8]);
#pragma unroll
        for (int ct = 0; ct < 8; ++ct) {
            int col = ct * 16 + l15;
            short8 wf = *reinterpret_cast<const short8*>(&Wt[(col * 16 + (kc ^ (col & 7))) * 8]);
            // swapped: A=W-frag, B=X-frag -> D[wcol][node]
            acc[ct] = __builtin_amdgcn_mfma_f32_16x16x32_bf16(wf, xf, acc[ct], 0, 0, 0);
        }
    }
    __syncthreads();   // done reading Xb

    // epilogue: lane holds node = w*16+l15, wcols = ct*16 + kg*4 + {0..3}
    unsigned int* Xo = reinterpret_cast<unsigned int*>(Xb);  // [64 rows][32 dwords]
    const int node = w * 16 + l15;
    const int gnode = rb + node;
    float dv = (gnode < NN) ? dinv[gnode] : 0.f;
#pragma unroll
    for (int ct = 0; ct < 8; ++ct) {
        unsigned int d = __builtin_amdgcn_cvt_pk_fp8_f32(acc[ct][0] * dv, acc[ct][1] * dv, 0u, false);
        d = __builtin_amdgcn_cvt_pk_fp8_f32(acc[ct][2] * dv, acc[ct][3] * dv, d, true);
        Xo[node * 32 + ((ct * 4 + kg) ^ ((node & 7) << 2))] = d;
    }
    __syncthreads();

    // coalesced fp8 store: 8 x uint4 per row
    for (int idx = tid; idx < 64 * 8; idx += 256) {
        int row = idx >> 3, kc = idx & 7;
        int grow = rb + row;
        if (grow < NN)
            out8[(size_t)grow * 8 + kc] =
                reinterpret_cast<const uint4*>(Xo)[row * 8 + (kc ^ (row & 7))];
    }
}

// ------- gather-reduce (fp8 rows): out[n] = dinv[n]*(g[n] + sum g[src]) + b -------
// 8 lanes per node; each lane covers 16 cols (one uint4 of fp8).
template <bool POOL>
__global__ __launch_bounds__(256) void k_gather(const uint4* __restrict__ g8,
                                                const int* __restrict__ esrc,
                                                const int* __restrict__ rowptr,
                                                const int* __restrict__ degp,
                                                const float* __restrict__ dinv,
                                                const float* __restrict__ bias,
                                                uint4* __restrict__ out16,
                                                float* __restrict__ ppart) {
    int t = blockIdx.x * 256 + threadIdx.x;
    int n = t >> 3;
    int c = t & 7;           // 16-col chunk
    int j0 = rowptr[n], j1 = j0 + degp[n];
    float a[16];
    uint4 sv = g8[(size_t)n * 8 + c];
    {
        f32x2 p;
        p = __builtin_amdgcn_cvt_pk_f32_fp8(sv.x, false); a[0] = p[0];  a[1] = p[1];
        p = __builtin_amdgcn_cvt_pk_f32_fp8(sv.x, true);  a[2] = p[0];  a[3] = p[1];
        p = __builtin_amdgcn_cvt_pk_f32_fp8(sv.y, false); a[4] = p[0];  a[5] = p[1];
        p = __builtin_amdgcn_cvt_pk_f32_fp8(sv.y, true);  a[6] = p[0];  a[7] = p[1];
        p = __builtin_amdgcn_cvt_pk_f32_fp8(sv.z, false); a[8] = p[0];  a[9] = p[1];
        p = __builtin_amdgcn_cvt_pk_f32_fp8(sv.z, true);  a[10] = p[0]; a[11] = p[1];
        p = __builtin_amdgcn_cvt_pk_f32_fp8(sv.w, false); a[12] = p[0]; a[13] = p[1];
        p = __builtin_amdgcn_cvt_pk_f32_fp8(sv.w, true);  a[14] = p[0]; a[15] = p[1];
    }
    int j = j0;
    for (; j + 4 <= j1; j += 4) {
        int s0 = esrc[j], s1 = esrc[j + 1], s2 = esrc[j + 2], s3 = esrc[j + 3];
        uint4 v0 = g8[(size_t)s0 * 8 + c];
        uint4 v1 = g8[(size_t)s1 * 8 + c];
        uint4 v2 = g8[(size_t)s2 * 8 + c];
        uint4 v3 = g8[(size_t)s3 * 8 + c];
        accp8(v0.x, a); accp8(v0.y, a + 4); accp8(v0.z, a + 8); accp8(v0.w, a + 12);
        accp8(v1.x, a); accp8(v1.y, a + 4); accp8(v1.z, a + 8); accp8(v1.w, a + 12);
        accp8(v2.x, a); accp8(v2.y, a + 4); accp8(v2.z, a + 8); accp8(v2.w, a + 12);
        accp8(v3.x, a); accp8(v3.y, a + 4); accp8(v3.z, a + 8); accp8(v3.w, a + 12);
    }
    for (; j < j1; ++j) {
        uint4 v = g8[(size_t)esrc[j] * 8 + c];
        accp8(v.x, a); accp8(v.y, a + 4); accp8(v.z, a + 8); accp8(v.w, a + 12);
    }
    float di = dinv[n];
    float r[16];
    const float4* bp = reinterpret_cast<const float4*>(bias + c * 16);
#pragma unroll
    for (int q = 0; q < 4; ++q) {
        float4 bb = bp[q];
        r[q * 4 + 0] = fmaf(a[q * 4 + 0], di, bb.x);
        r[q * 4 + 1] = fmaf(a[q * 4 + 1], di, bb.y);
        r[q * 4 + 2] = fmaf(a[q * 4 + 2], di, bb.z);
        r[q * 4 + 3] = fmaf(a[q * 4 + 3], di, bb.w);
    }
    if constexpr (!POOL) {
        // bf16 out (next gemm input): 2 x uint4 per lane, coalesced
        uint4 o0, o1;
        o0.x = f2b(r[0]) | (f2b(r[1]) << 16);
        o0.y = f2b(r[2]) | (f2b(r[3]) << 16);
        o0.z = f2b(r[4]) | (f2b(r[5]) << 16);
        o0.w = f2b(r[6]) | (f2b(r[7]) << 16);
        o1.x = f2b(r[8]) | (f2b(r[9]) << 16);
        o1.y = f2b(r[10]) | (f2b(r[11]) << 16);
        o1.z = f2b(r[12]) | (f2b(r[13]) << 16);
        o1.w = f2b(r[14]) | (f2b(r[15]) << 16);
        out16[(size_t)n * 16 + c * 2] = o0;
        out16[(size_t)n * 16 + c * 2 + 1] = o1;
    } else {
        __shared__ float red[32][132];
        int slot = threadIdx.x >> 3;
#pragma unroll
        for (int k = 0; k < 16; ++k)
            red[slot][c * 16 + k] = fmaxf(r[k], 0.f);
        __syncthreads();
        if (threadIdx.x < 128) {
            float s = 0.f;
#pragma unroll
            for (int sl = 0; sl < 32; ++sl) s += red[sl][threadIdx.x];
            ppart[blockIdx.x * 128 + threadIdx.x] = s;
        }
    }
}

// ---------------- pool partial reduce: 3125x128 -> 128x128 ----------------
__global__ void k_red1(const float* __restrict__ ppart, float* __restrict__ pp2) {
    int j = blockIdx.x;       // 0..127
    int c = threadIdx.x;      // 0..127
    int p0 = j * 25, p1 = min(p0 + 25, NGATB);
    float s = 0.f;
    for (int p = p0; p < p1; ++p) s += ppart[p * 128 + c];
    pp2[j * 128 + c] = s;
}

// ---------------- final: reduce 128x128 + fc + softmax ----------------
__global__ void k_final(const float* __restrict__ pp2, const float* __restrict__ fc_w,
                        const float* __restrict__ fc_b, float* __restrict__ out) {
    __shared__ float part[4][DIM];
    int c = threadIdx.x;  // 0..127
    float s = 0.f;
    for (int j = 0; j < 128; ++j) s += pp2[j * 128 + c];
    float p = s * (1.f / NN);
    for (int j = 0; j < 4; ++j) part[j][c] = p * fc_w[c * 4 + j];
    __syncthreads();
    if (c == 0) {
        float l[4];
        for (int j = 0; j < 4; ++j) {
            float acc = fc_b[j];
            for (int i = 0; i < DIM; ++i) acc += part[j][i];
            l[j] = acc;
        }
        float m = fmaxf(fmaxf(l[0], l[1]), fmaxf(l[2], l[3]));
        float e[4], Z = 0.f;
        for (int j = 0; j < 4; ++j) { e[j] = expf(l[j] - m); Z += e[j]; }
        for (int j = 0; j < 4; ++j) out[j] = e[j] / Z;
    }
}

extern "C" void kernel_launch(void* const* d_in, const int* in_sizes, int n_in,
                              void* d_out, int out_size, void* d_ws, size_t ws_size,
                              hipStream_t stream) {
    const float* x   = (const float*)d_in[0];
    const int*   ei  = (const int*)d_in[1];
    const float* W1  = (const float*)d_in[2];
    const float* b1  = (const float*)d_in[3];
    const float* W2  = (const float*)d_in[4];
    const float* b2  = (const float*)d_in[5];
    const float* W3  = (const float*)d_in[6];
    const float* b3  = (const float*)d_in[7];
    const float* fcw = (const float*)d_in[8];
    const float* fcb = (const float*)d_in[9];
    float* out = (float*)d_out;

    char* ws = (char*)d_ws;
    void*  A8      = (void*)(ws);                        // 12,800,000 B (fp8 g)
    void*  B16     = (void*)(ws + 12800000);             // 25,600,000 B (bf16 act)
    float* dinv    = (float*)(ws + 38400000);            //    400,000 B
    int*   rowptr  = (int*)  (ws + 38800000);            //    400,000 B
    int*   degp    = (int*)  (ws + 39200000);            //    400,000 B
    int*   esrc    = (int*)  (ws + 39600000);            //  7,225,344 B (196*9216*4)
    unsigned int* epk = (unsigned int*)(ws + 46825344);  //  7,225,344 B
    int*   gcursor = (int*)  (ws + 54050688);            //      1,024 B
    float* ppart   = (float*)(ws + 54051712);            //  1,600,000 B (3125*128)
    float* pp2     = (float*)(ws + 55651712);            //     65,536 B
    uint4* Wg      = (uint4*)(ws + 55717248);            //     98,304 B

    const int* src = ei;
    const int* dst = ei + NE;

    // ---- CSR build: single-pass arena partition ----
    k_initcur<<<1, 256, 0, stream>>>(gcursor);
    k_passA<<<PA_GRID, 256, 0, stream>>>(src, dst, gcursor, epk);
    k_passB<<<NBKT, 256, 0, stream>>>(epk, gcursor, rowptr, dinv, degp, esrc);
    k_wcvt<<<24, 256, 0, stream>>>(W1, W2, W3, Wg);

    const int GB = (NN + 63) / 64;  // 1563
    // ---- layer 1 ----
    k_gemm<true><<<GB, 256, 0, stream>>>(x, Wg, dinv, (uint4*)A8);
    k_gather<false><<<NGATB, 256, 0, stream>>>((const uint4*)A8, esrc, rowptr, degp, dinv, b1, (uint4*)B16, nullptr);
    // ---- layer 2 ----
    k_gemm<false><<<GB, 256, 0, stream>>>(B16, Wg + 2048, dinv, (uint4*)A8);
    k_gather<false><<<NGATB, 256, 0, stream>>>((const uint4*)A8, esrc, rowptr, degp, dinv, b2, (uint4*)B16, nullptr);
    // ---- layer 3 (fused relu + pool partials) ----
    k_gemm<false><<<GB, 256, 0, stream>>>(B16, Wg + 4096, dinv, (uint4*)A8);
    k_gather<true><<<NGATB, 256, 0, stream>>>((const uint4*)A8, esrc, rowptr, degp, dinv, b3, nullptr, ppart);

    // ---- pool reduce + fc + softmax ----
    k_red1<<<128, 128, 0, stream>>>(ppart, pp2);
    k_final<<<1, 128, 0, stream>>>(pp2, fcw, fcb, out);
}